// Round 1
// baseline (8652.058 us; speedup 1.0000x reference)
//
#include <hip/hip_runtime.h>

#define HID 128
#define NGRAPH 512
#define NLAYERS 3
#define BN_EPS 1e-5f

// ---------------------------------------------------------------------------
// setup: identity affine (for layer 0) + zero BN stats
// ---------------------------------------------------------------------------
__global__ void k_setup(float* __restrict__ id_scale, float* __restrict__ id_shift,
                        float* __restrict__ stats) {
    int t = threadIdx.x;              // 256 threads
    if (t < 128) { id_scale[t] = 1.0f; id_shift[t] = 0.0f; }
    for (int l = 0; l < NLAYERS; ++l) stats[l * 256 + t] = 0.0f;  // sum[128]+sq[128] per layer
}

// ---------------------------------------------------------------------------
// z0 = (1+eps) * affine(h_in)   (affine = previous layer's folded batchnorm)
// ---------------------------------------------------------------------------
__global__ void k_z0_init(const float4* __restrict__ hin, const float4* __restrict__ sc4,
                          const float4* __restrict__ sh4, const float* __restrict__ eps_gin,
                          int layer, float4* __restrict__ z0, int n4) {
    int i = blockIdx.x * blockDim.x + threadIdx.x;
    if (i >= n4) return;
    float e = 1.0f + eps_gin[layer];
    int q = i & 31;                  // float4 index within a 128-float row
    float4 h = hin[i];
    float4 s = sc4[q];
    float4 b = sh4[q];
    float4 r;
    r.x = e * (h.x * s.x + b.x);
    r.y = e * (h.y * s.y + b.y);
    r.z = e * (h.z * s.z + b.z);
    r.w = e * (h.w * s.w + b.w);
    z0[i] = r;
}

// ---------------------------------------------------------------------------
// edge aggregation: z0[dst] += affine(h_in[src]); 32 threads (8 float4) per edge
// ---------------------------------------------------------------------------
__global__ void k_edge_agg(const int* __restrict__ src, const int* __restrict__ dst, int E,
                           const float4* __restrict__ hin, const float4* __restrict__ sc4,
                           const float4* __restrict__ sh4, float* __restrict__ z0) {
    long long gid = (long long)blockIdx.x * blockDim.x + threadIdx.x;
    if (gid >= (long long)E * 32) return;
    int e = (int)(gid >> 5);
    int q = (int)(gid & 31);
    int s = src[e];
    int d = dst[e];
    float4 v = hin[(size_t)s * 32 + q];
    float4 a = sc4[q];
    float4 b = sh4[q];
    float* zp = z0 + (size_t)d * HID + q * 4;
    unsafeAtomicAdd(zp + 0, v.x * a.x + b.x);
    unsafeAtomicAdd(zp + 1, v.y * a.y + b.y);
    unsafeAtomicAdd(zp + 2, v.z * a.z + b.z);
    unsafeAtomicAdd(zp + 3, v.w * a.w + b.w);
}

// ---------------------------------------------------------------------------
// fused per-layer MLP: h_out = relu(relu(z0@W1+b1)@W2+b2), + BN stats (sum, sumsq)
// Block: 256 threads, 64 rows. LDS: A-tile (xor-swizzled) 32KB + W k-chunk 32KB.
// z1 never leaves LDS. Thread micro-tile: 4 rows x 8 cols.
// ---------------------------------------------------------------------------
__global__ __launch_bounds__(256) void k_gin_mlp(
        const float* __restrict__ A, const float* __restrict__ W1, const float* __restrict__ b1,
        const float* __restrict__ W2, const float* __restrict__ b2,
        float* __restrict__ Hout, float* __restrict__ stat_sum, float* __restrict__ stat_sq, int N) {
    __shared__ float As[64][128];   // As[r][k ^ ((r&3)*8)] = A[row0+r][k]
    __shared__ float Ws[64][128];   // one 64-row k-chunk of W

    const int t = threadIdx.x;
    const int row0 = blockIdx.x * 64;
    int valid = N - row0; if (valid > 64) valid = 64;

    // ---- stage A tile (swizzled) ----
    {
        const float4* A4 = (const float4*)A;
        #pragma unroll
        for (int i = 0; i < 8; ++i) {
            int idx4 = t + i * 256;          // 0..2047
            int r = idx4 >> 5;               // 0..63
            int k4 = idx4 & 31;              // float4 col
            float4 v = make_float4(0.f, 0.f, 0.f, 0.f);
            if (r < valid) v = A4[(size_t)(row0 + r) * 32 + k4];
            int kx = (k4 * 4) ^ ((r & 3) * 8);
            *(float4*)&As[r][kx] = v;
        }
    }

    const int rg = t >> 4;           // 0..15
    const int cg = t & 15;           // 0..15
    const int r0 = rg * 4;
    const int c0 = cg * 8;

    float acc[4][8];
    #pragma unroll
    for (int i = 0; i < 4; ++i)
        #pragma unroll
        for (int j = 0; j < 8; ++j) acc[i][j] = 0.f;

    // ---- GEMM1: z1 = z0 @ W1 (k in two 64-chunks) ----
    for (int ch = 0; ch < 2; ++ch) {
        __syncthreads();
        const float4* W4 = (const float4*)(W1 + (size_t)ch * 64 * HID);
        #pragma unroll
        for (int i = 0; i < 8; ++i) {
            int idx4 = t + i * 256;
            *(float4*)&Ws[idx4 >> 5][(idx4 & 31) * 4] = W4[idx4];
        }
        __syncthreads();
        for (int k = 0; k < 64; ++k) {
            int kk = ch * 64 + k;
            float a[4];
            #pragma unroll
            for (int i = 0; i < 4; ++i) a[i] = As[r0 + i][kk ^ (i * 8)];
            float w[8];
            *(float4*)&w[0] = *(const float4*)&Ws[k][c0];
            *(float4*)&w[4] = *(const float4*)&Ws[k][c0 + 4];
            #pragma unroll
            for (int i = 0; i < 4; ++i)
                #pragma unroll
                for (int j = 0; j < 8; ++j) acc[i][j] = fmaf(a[i], w[j], acc[i][j]);
        }
    }

    // ---- bias+relu, z1 tile back into As (same swizzle) ----
    float bv[8];
    *(float4*)&bv[0] = *(const float4*)&b1[c0];
    *(float4*)&bv[4] = *(const float4*)&b1[c0 + 4];
    __syncthreads();   // all As(z0) reads done
    #pragma unroll
    for (int i = 0; i < 4; ++i) {
        int r = r0 + i;
        float z[8];
        #pragma unroll
        for (int j = 0; j < 8; ++j) z[j] = fmaxf(acc[i][j] + bv[j], 0.f);
        int swz = i * 8;   // (r&3)*8
        *(float4*)&As[r][c0 ^ swz]       = *(float4*)&z[0];
        *(float4*)&As[r][(c0 + 4) ^ swz] = *(float4*)&z[4];
    }
    #pragma unroll
    for (int i = 0; i < 4; ++i)
        #pragma unroll
        for (int j = 0; j < 8; ++j) acc[i][j] = 0.f;

    // ---- GEMM2: z2 = z1 @ W2 ----
    for (int ch = 0; ch < 2; ++ch) {
        __syncthreads();
        const float4* W4 = (const float4*)(W2 + (size_t)ch * 64 * HID);
        #pragma unroll
        for (int i = 0; i < 8; ++i) {
            int idx4 = t + i * 256;
            *(float4*)&Ws[idx4 >> 5][(idx4 & 31) * 4] = W4[idx4];
        }
        __syncthreads();
        for (int k = 0; k < 64; ++k) {
            int kk = ch * 64 + k;
            float a[4];
            #pragma unroll
            for (int i = 0; i < 4; ++i) a[i] = As[r0 + i][kk ^ (i * 8)];
            float w[8];
            *(float4*)&w[0] = *(const float4*)&Ws[k][c0];
            *(float4*)&w[4] = *(const float4*)&Ws[k][c0 + 4];
            #pragma unroll
            for (int i = 0; i < 4; ++i)
                #pragma unroll
                for (int j = 0; j < 8; ++j) acc[i][j] = fmaf(a[i], w[j], acc[i][j]);
        }
    }

    // ---- epilogue: bias+relu, write h, BN partial stats ----
    float bv2[8];
    *(float4*)&bv2[0] = *(const float4*)&b2[c0];
    *(float4*)&bv2[4] = *(const float4*)&b2[c0 + 4];
    float csum[8], csq[8];
    #pragma unroll
    for (int j = 0; j < 8; ++j) { csum[j] = 0.f; csq[j] = 0.f; }
    #pragma unroll
    for (int i = 0; i < 4; ++i) {
        int grow = row0 + r0 + i;
        if (grow < N) {
            float z[8];
            #pragma unroll
            for (int j = 0; j < 8; ++j) {
                z[j] = fmaxf(acc[i][j] + bv2[j], 0.f);
                csum[j] += z[j];
                csq[j]  += z[j] * z[j];
            }
            *(float4*)&Hout[(size_t)grow * HID + c0]     = *(float4*)&z[0];
            *(float4*)&Hout[(size_t)grow * HID + c0 + 4] = *(float4*)&z[4];
        }
    }
    // deterministic block reduction via LDS (reuse As rows): part_sum[rg][c], part_sq[16+rg][c]
    __syncthreads();   // all As(z1) reads done
    #pragma unroll
    for (int j = 0; j < 8; ++j) {
        As[rg][c0 + j]      = csum[j];
        As[16 + rg][c0 + j] = csq[j];
    }
    __syncthreads();
    if (t < 128) {
        float s = 0.f, q = 0.f;
        #pragma unroll
        for (int g = 0; g < 16; ++g) { s += As[g][t]; q += As[16 + g][t]; }
        unsafeAtomicAdd(&stat_sum[t], s);
        unsafeAtomicAdd(&stat_sq[t], q);
    }
}

// ---------------------------------------------------------------------------
// fold BN into per-feature scale/shift
// ---------------------------------------------------------------------------
__global__ void k_bn_fin(const float* __restrict__ stat_sum, const float* __restrict__ stat_sq,
                         const float* __restrict__ gamma, const float* __restrict__ beta,
                         int layer, int N, float* __restrict__ scale, float* __restrict__ shift) {
    int f = threadIdx.x;   // 128
    float invn = 1.0f / (float)N;
    float mu = stat_sum[f] * invn;
    float var = stat_sq[f] * invn - mu * mu;
    float inv = rsqrtf(var + BN_EPS);
    float sc = gamma[layer * HID + f] * inv;
    scale[f] = sc;
    shift[f] = beta[layer * HID + f] - mu * sc;
}

// ---------------------------------------------------------------------------
// global mean pool over concat(h0,h1,h2) with BN affine folded out of the loop
// one block per graph, 384 threads (one per concat feature)
// ---------------------------------------------------------------------------
__global__ __launch_bounds__(384) void k_pool(const int* __restrict__ batch, int N,
                       const float* __restrict__ h0, const float* __restrict__ h1,
                       const float* __restrict__ h2, const float* __restrict__ ss,
                       float* __restrict__ g_feat) {
    int g = blockIdx.x;
    int f = threadIdx.x;            // 0..383
    int start, end;
    { int lo = 0, hi = N; while (lo < hi) { int m = (lo + hi) >> 1; if (batch[m] < g) lo = m + 1; else hi = m; } start = lo; }
    { int lo = start, hi = N; while (lo < hi) { int m = (lo + hi) >> 1; if (batch[m] < g + 1) lo = m + 1; else hi = m; } end = lo; }
    int l = f >> 7, c = f & 127;
    const float* hb = (l == 0) ? h0 : (l == 1) ? h1 : h2;
    float sc = ss[l * 256 + c];
    float sh = ss[l * 256 + 128 + c];
    float sum = 0.f;
    for (int i = start; i < end; ++i) sum += hb[(size_t)i * HID + c];
    float cnt = (float)(end - start);
    g_feat[g * 384 + f] = (sum * sc + sh * cnt) / fmaxf(cnt, 1.0f);
}

// ---------------------------------------------------------------------------
// final MLP: out = relu(g_feat @ lin1 + b1) @ lin2 + b2 ; one block per graph
// ---------------------------------------------------------------------------
__global__ __launch_bounds__(128) void k_mlp(const float* __restrict__ g_feat,
                     const float* __restrict__ w1, const float* __restrict__ b1,
                     const float* __restrict__ w2, const float* __restrict__ b2,
                     float* __restrict__ out) {
    __shared__ float gl[384];
    __shared__ float hh[128];
    int g = blockIdx.x, t = threadIdx.x;   // 128 threads
    for (int i = t; i < 384; i += 128) gl[i] = g_feat[g * 384 + i];
    __syncthreads();
    float acc = b1[t];
    for (int k = 0; k < 384; ++k) acc = fmaf(gl[k], w1[k * HID + t], acc);
    hh[t] = fmaxf(acc, 0.f);
    __syncthreads();
    if (t < 10) {
        float a2 = b2[t];
        for (int k = 0; k < 128; ++k) a2 = fmaf(hh[k], w2[k * 10 + t], a2);
        out[g * 10 + t] = a2;
    }
}

// ---------------------------------------------------------------------------
extern "C" void kernel_launch(void* const* d_in, const int* in_sizes, int n_in,
                              void* d_out, int out_size, void* d_ws, size_t ws_size,
                              hipStream_t stream) {
    const float* x     = (const float*)d_in[0];
    const int*   ei    = (const int*)d_in[1];
    const int*   batch = (const int*)d_in[2];
    const float* W1    = (const float*)d_in[3];
    const float* b1    = (const float*)d_in[4];
    const float* W2    = (const float*)d_in[5];
    const float* b2    = (const float*)d_in[6];
    const float* gamma = (const float*)d_in[7];
    const float* beta  = (const float*)d_in[8];
    const float* epsg  = (const float*)d_in[9];
    const float* l1w   = (const float*)d_in[10];
    const float* l1b   = (const float*)d_in[11];
    const float* l2w   = (const float*)d_in[12];
    const float* l2b   = (const float*)d_in[13];

    const int N = in_sizes[0] / HID;
    const int E = in_sizes[1] / 2;
    const int* src = ei;
    const int* dst = ei + E;

    float* w = (float*)d_ws;
    const size_t NF = (size_t)N * HID;
    float* zbuf   = w;
    float* h[3]   = { w + NF, w + 2 * NF, w + 3 * NF };
    float* stats  = w + 4 * NF;       // 3 * 256  (sum | sumsq per layer)
    float* ss     = stats + 768;      // 3 * 256  (scale | shift per layer)
    float* idaff  = ss + 768;         // 256      (identity scale | shift)
    float* g_feat = idaff + 256;      // 512 * 384

    k_setup<<<1, 256, 0, stream>>>(idaff, idaff + 128, stats);

    const int n4 = N * 32;
    for (int l = 0; l < NLAYERS; ++l) {
        const float* hin = (l == 0) ? x : h[l - 1];
        const float* asc = (l == 0) ? idaff : (ss + (l - 1) * 256);
        const float* ash = asc + 128;

        k_z0_init<<<(n4 + 255) / 256, 256, 0, stream>>>(
            (const float4*)hin, (const float4*)asc, (const float4*)ash,
            epsg, l, (float4*)zbuf, n4);

        long long tot = (long long)E * 32;
        k_edge_agg<<<(int)((tot + 255) / 256), 256, 0, stream>>>(
            src, dst, E, (const float4*)hin, (const float4*)asc, (const float4*)ash, zbuf);

        k_gin_mlp<<<(N + 63) / 64, 256, 0, stream>>>(
            zbuf, W1 + (size_t)l * HID * HID, b1 + l * HID,
            W2 + (size_t)l * HID * HID, b2 + l * HID,
            h[l], stats + l * 256, stats + l * 256 + 128, N);

        k_bn_fin<<<1, 128, 0, stream>>>(
            stats + l * 256, stats + l * 256 + 128, gamma, beta, l, N,
            ss + l * 256, ss + l * 256 + 128);
    }

    k_pool<<<NGRAPH, 384, 0, stream>>>(batch, N, h[0], h[1], h[2], ss, g_feat);
    k_mlp<<<NGRAPH, 128, 0, stream>>>(g_feat, l1w, l1b, l2w, l2b, (float*)d_out);
}

// Round 2
// 1355.027 us; speedup vs baseline: 6.3852x; 6.3852x over previous
//
#include <hip/hip_runtime.h>

#define HID 128
#define NGRAPH 512
#define NLAYERS 3
#define BN_EPS 1e-5f

// ---------------------------------------------------------------------------
// setup: identity affine (for layer 0) + zero BN stats
// ---------------------------------------------------------------------------
__global__ void k_setup(float* __restrict__ id_scale, float* __restrict__ id_shift,
                        float* __restrict__ stats) {
    int t = threadIdx.x;              // 256 threads
    if (t < 128) { id_scale[t] = 1.0f; id_shift[t] = 0.0f; }
    for (int l = 0; l < NLAYERS; ++l) stats[l * 256 + t] = 0.0f;  // sum[128]+sq[128] per layer
}

// ---------------------------------------------------------------------------
// CSR build: histogram of dst
// ---------------------------------------------------------------------------
__global__ void k_hist(const int* __restrict__ dst, int E, int* __restrict__ counts) {
    int i = blockIdx.x * blockDim.x + threadIdx.x;
    if (i < E) atomicAdd(&counts[dst[i]], 1);
}

// single-block scan: rowptr (exclusive) + cursor copy
__global__ __launch_bounds__(1024) void k_scan(const int* __restrict__ counts, int N,
                       int* __restrict__ rowptr, int* __restrict__ cursor) {
    __shared__ int sums[1024];
    int t = threadIdx.x;
    int chunk = (N + 1023) >> 10;
    int beg = t * chunk, end = beg + chunk; if (end > N) end = N; if (beg > N) beg = N;
    int s = 0;
    for (int i = beg; i < end; ++i) s += counts[i];
    sums[t] = s;
    __syncthreads();
    for (int off = 1; off < 1024; off <<= 1) {
        int v = (t >= off) ? sums[t - off] : 0;
        __syncthreads();
        sums[t] += v;
        __syncthreads();
    }
    int run = (t == 0) ? 0 : sums[t - 1];
    for (int i = beg; i < end; ++i) {
        int c = counts[i];
        rowptr[i] = run; cursor[i] = run;
        run += c;
    }
    if (t == 1023) rowptr[N] = sums[1023];
}

__global__ void k_scatter(const int* __restrict__ src, const int* __restrict__ dst, int E,
                          int* __restrict__ cursor, int* __restrict__ csr_src) {
    int i = blockIdx.x * blockDim.x + threadIdx.x;
    if (i < E) {
        int pos = atomicAdd(&cursor[dst[i]], 1);
        csr_src[pos] = src[i];
    }
}

// ---------------------------------------------------------------------------
// CSR aggregation, fused with self term + folded BN affine of the INPUT:
//   z0[i] = sc * ((1+eps)*h_i + sum_{j->i} h_j) + (1+eps+deg)*sh
// one wave (64 lanes, float2 each) per node; 4 nodes per 256-block.
// No atomics: each node row is written exactly once.
// ---------------------------------------------------------------------------
__global__ __launch_bounds__(256) void k_agg_csr(
        const int* __restrict__ rowptr, const int* __restrict__ csr_src,
        const float2* __restrict__ hin, const float* __restrict__ ss,
        const float* __restrict__ eps_gin, int layer, float2* __restrict__ z0, int N) {
    int node = blockIdx.x * 4 + (threadIdx.x >> 6);
    if (node >= N) return;
    int f = threadIdx.x & 63;                      // float2 lane
    float2 sc = ((const float2*)ss)[f];
    float2 sh = ((const float2*)(ss + HID))[f];
    float e1 = 1.0f + eps_gin[layer];
    int beg = rowptr[node], end = rowptr[node + 1];
    float2 hself = hin[(size_t)node * 64 + f];
    float sx = e1 * hself.x, sy = e1 * hself.y;
    int p = beg;
    for (; p + 1 < end; p += 2) {
        int s0 = csr_src[p], s1 = csr_src[p + 1];
        float2 v0 = hin[(size_t)s0 * 64 + f];
        float2 v1 = hin[(size_t)s1 * 64 + f];
        sx += v0.x + v1.x;
        sy += v0.y + v1.y;
    }
    if (p < end) {
        int s0 = csr_src[p];
        float2 v0 = hin[(size_t)s0 * 64 + f];
        sx += v0.x; sy += v0.y;
    }
    float c = e1 + (float)(end - beg);
    float2 r;
    r.x = sc.x * sx + c * sh.x;
    r.y = sc.y * sy + c * sh.y;
    z0[(size_t)node * 64 + f] = r;
}

// ---------------------------------------------------------------------------
// fused per-layer MLP: h_out = relu(relu(z0@W1+b1)@W2+b2), + BN stats (sum, sumsq)
// Block: 256 threads, 64 rows. LDS: A-tile (xor-swizzled) 32KB + W k-chunk 32KB.
// z1 never leaves LDS. Thread micro-tile: 4 rows x 8 cols.
// ---------------------------------------------------------------------------
__global__ __launch_bounds__(256) void k_gin_mlp(
        const float* __restrict__ A, const float* __restrict__ W1, const float* __restrict__ b1,
        const float* __restrict__ W2, const float* __restrict__ b2,
        float* __restrict__ Hout, float* __restrict__ stat_sum, float* __restrict__ stat_sq, int N) {
    __shared__ float As[64][128];   // As[r][k ^ ((r&3)*8)] = A[row0+r][k]
    __shared__ float Ws[64][128];   // one 64-row k-chunk of W

    const int t = threadIdx.x;
    const int row0 = blockIdx.x * 64;
    int valid = N - row0; if (valid > 64) valid = 64;

    // ---- stage A tile (swizzled) ----
    {
        const float4* A4 = (const float4*)A;
        #pragma unroll
        for (int i = 0; i < 8; ++i) {
            int idx4 = t + i * 256;          // 0..2047
            int r = idx4 >> 5;               // 0..63
            int k4 = idx4 & 31;              // float4 col
            float4 v = make_float4(0.f, 0.f, 0.f, 0.f);
            if (r < valid) v = A4[(size_t)(row0 + r) * 32 + k4];
            int kx = (k4 * 4) ^ ((r & 3) * 8);
            *(float4*)&As[r][kx] = v;
        }
    }

    const int rg = t >> 4;           // 0..15
    const int cg = t & 15;           // 0..15
    const int r0 = rg * 4;
    const int c0 = cg * 8;

    float acc[4][8];
    #pragma unroll
    for (int i = 0; i < 4; ++i)
        #pragma unroll
        for (int j = 0; j < 8; ++j) acc[i][j] = 0.f;

    // ---- GEMM1: z1 = z0 @ W1 (k in two 64-chunks) ----
    for (int ch = 0; ch < 2; ++ch) {
        __syncthreads();
        const float4* W4 = (const float4*)(W1 + (size_t)ch * 64 * HID);
        #pragma unroll
        for (int i = 0; i < 8; ++i) {
            int idx4 = t + i * 256;
            *(float4*)&Ws[idx4 >> 5][(idx4 & 31) * 4] = W4[idx4];
        }
        __syncthreads();
        for (int k = 0; k < 64; ++k) {
            int kk = ch * 64 + k;
            float a[4];
            #pragma unroll
            for (int i = 0; i < 4; ++i) a[i] = As[r0 + i][kk ^ (i * 8)];
            float w[8];
            *(float4*)&w[0] = *(const float4*)&Ws[k][c0];
            *(float4*)&w[4] = *(const float4*)&Ws[k][c0 + 4];
            #pragma unroll
            for (int i = 0; i < 4; ++i)
                #pragma unroll
                for (int j = 0; j < 8; ++j) acc[i][j] = fmaf(a[i], w[j], acc[i][j]);
        }
    }

    // ---- bias+relu, z1 tile back into As (same swizzle) ----
    float bv[8];
    *(float4*)&bv[0] = *(const float4*)&b1[c0];
    *(float4*)&bv[4] = *(const float4*)&b1[c0 + 4];
    __syncthreads();   // all As(z0) reads done
    #pragma unroll
    for (int i = 0; i < 4; ++i) {
        int r = r0 + i;
        float z[8];
        #pragma unroll
        for (int j = 0; j < 8; ++j) z[j] = fmaxf(acc[i][j] + bv[j], 0.f);
        int swz = i * 8;   // (r&3)*8
        *(float4*)&As[r][c0 ^ swz]       = *(float4*)&z[0];
        *(float4*)&As[r][(c0 + 4) ^ swz] = *(float4*)&z[4];
    }
    #pragma unroll
    for (int i = 0; i < 4; ++i)
        #pragma unroll
        for (int j = 0; j < 8; ++j) acc[i][j] = 0.f;

    // ---- GEMM2: z2 = z1 @ W2 ----
    for (int ch = 0; ch < 2; ++ch) {
        __syncthreads();
        const float4* W4 = (const float4*)(W2 + (size_t)ch * 64 * HID);
        #pragma unroll
        for (int i = 0; i < 8; ++i) {
            int idx4 = t + i * 256;
            *(float4*)&Ws[idx4 >> 5][(idx4 & 31) * 4] = W4[idx4];
        }
        __syncthreads();
        for (int k = 0; k < 64; ++k) {
            int kk = ch * 64 + k;
            float a[4];
            #pragma unroll
            for (int i = 0; i < 4; ++i) a[i] = As[r0 + i][kk ^ (i * 8)];
            float w[8];
            *(float4*)&w[0] = *(const float4*)&Ws[k][c0];
            *(float4*)&w[4] = *(const float4*)&Ws[k][c0 + 4];
            #pragma unroll
            for (int i = 0; i < 4; ++i)
                #pragma unroll
                for (int j = 0; j < 8; ++j) acc[i][j] = fmaf(a[i], w[j], acc[i][j]);
        }
    }

    // ---- epilogue: bias+relu, write h, BN partial stats ----
    float bv2[8];
    *(float4*)&bv2[0] = *(const float4*)&b2[c0];
    *(float4*)&bv2[4] = *(const float4*)&b2[c0 + 4];
    float csum[8], csq[8];
    #pragma unroll
    for (int j = 0; j < 8; ++j) { csum[j] = 0.f; csq[j] = 0.f; }
    #pragma unroll
    for (int i = 0; i < 4; ++i) {
        int grow = row0 + r0 + i;
        if (grow < N) {
            float z[8];
            #pragma unroll
            for (int j = 0; j < 8; ++j) {
                z[j] = fmaxf(acc[i][j] + bv2[j], 0.f);
                csum[j] += z[j];
                csq[j]  += z[j] * z[j];
            }
            *(float4*)&Hout[(size_t)grow * HID + c0]     = *(float4*)&z[0];
            *(float4*)&Hout[(size_t)grow * HID + c0 + 4] = *(float4*)&z[4];
        }
    }
    // deterministic block reduction via LDS (reuse As rows)
    __syncthreads();   // all As(z1) reads done
    #pragma unroll
    for (int j = 0; j < 8; ++j) {
        As[rg][c0 + j]      = csum[j];
        As[16 + rg][c0 + j] = csq[j];
    }
    __syncthreads();
    if (t < 128) {
        float s = 0.f, q = 0.f;
        #pragma unroll
        for (int g = 0; g < 16; ++g) { s += As[g][t]; q += As[16 + g][t]; }
        unsafeAtomicAdd(&stat_sum[t], s);
        unsafeAtomicAdd(&stat_sq[t], q);
    }
}

// ---------------------------------------------------------------------------
// fold BN into per-feature scale/shift
// ---------------------------------------------------------------------------
__global__ void k_bn_fin(const float* __restrict__ stat_sum, const float* __restrict__ stat_sq,
                         const float* __restrict__ gamma, const float* __restrict__ beta,
                         int layer, int N, float* __restrict__ scale, float* __restrict__ shift) {
    int f = threadIdx.x;   // 128
    float invn = 1.0f / (float)N;
    float mu = stat_sum[f] * invn;
    float var = stat_sq[f] * invn - mu * mu;
    float inv = rsqrtf(var + BN_EPS);
    float sc = gamma[layer * HID + f] * inv;
    scale[f] = sc;
    shift[f] = beta[layer * HID + f] - mu * sc;
}

// ---------------------------------------------------------------------------
// global mean pool over concat(h0,h1,h2) with BN affine folded out of the loop
// ---------------------------------------------------------------------------
__global__ __launch_bounds__(384) void k_pool(const int* __restrict__ batch, int N,
                       const float* __restrict__ h0, const float* __restrict__ h1,
                       const float* __restrict__ h2, const float* __restrict__ ss,
                       float* __restrict__ g_feat) {
    int g = blockIdx.x;
    int f = threadIdx.x;            // 0..383
    int start, end;
    { int lo = 0, hi = N; while (lo < hi) { int m = (lo + hi) >> 1; if (batch[m] < g) lo = m + 1; else hi = m; } start = lo; }
    { int lo = start, hi = N; while (lo < hi) { int m = (lo + hi) >> 1; if (batch[m] < g + 1) lo = m + 1; else hi = m; } end = lo; }
    int l = f >> 7, c = f & 127;
    const float* hb = (l == 0) ? h0 : (l == 1) ? h1 : h2;
    float sc = ss[l * 256 + c];
    float sh = ss[l * 256 + 128 + c];
    float sum = 0.f;
    for (int i = start; i < end; ++i) sum += hb[(size_t)i * HID + c];
    float cnt = (float)(end - start);
    g_feat[g * 384 + f] = (sum * sc + sh * cnt) / fmaxf(cnt, 1.0f);
}

// ---------------------------------------------------------------------------
// final MLP: out = relu(g_feat @ lin1 + b1) @ lin2 + b2 ; one block per graph
// ---------------------------------------------------------------------------
__global__ __launch_bounds__(128) void k_mlp(const float* __restrict__ g_feat,
                     const float* __restrict__ w1, const float* __restrict__ b1,
                     const float* __restrict__ w2, const float* __restrict__ b2,
                     float* __restrict__ out) {
    __shared__ float gl[384];
    __shared__ float hh[128];
    int g = blockIdx.x, t = threadIdx.x;   // 128 threads
    for (int i = t; i < 384; i += 128) gl[i] = g_feat[g * 384 + i];
    __syncthreads();
    float acc = b1[t];
    for (int k = 0; k < 384; ++k) acc = fmaf(gl[k], w1[k * HID + t], acc);
    hh[t] = fmaxf(acc, 0.f);
    __syncthreads();
    if (t < 10) {
        float a2 = b2[t];
        for (int k = 0; k < 128; ++k) a2 = fmaf(hh[k], w2[k * 10 + t], a2);
        out[g * 10 + t] = a2;
    }
}

// ---------------------------------------------------------------------------
extern "C" void kernel_launch(void* const* d_in, const int* in_sizes, int n_in,
                              void* d_out, int out_size, void* d_ws, size_t ws_size,
                              hipStream_t stream) {
    const float* x     = (const float*)d_in[0];
    const int*   ei    = (const int*)d_in[1];
    const int*   batch = (const int*)d_in[2];
    const float* W1    = (const float*)d_in[3];
    const float* b1    = (const float*)d_in[4];
    const float* W2    = (const float*)d_in[5];
    const float* b2    = (const float*)d_in[6];
    const float* gamma = (const float*)d_in[7];
    const float* beta  = (const float*)d_in[8];
    const float* epsg  = (const float*)d_in[9];
    const float* l1w   = (const float*)d_in[10];
    const float* l1b   = (const float*)d_in[11];
    const float* l2w   = (const float*)d_in[12];
    const float* l2b   = (const float*)d_in[13];

    const int N = in_sizes[0] / HID;
    const int E = in_sizes[1] / 2;
    const int* src = ei;
    const int* dst = ei + E;

    float* w = (float*)d_ws;
    const size_t NF = (size_t)N * HID;
    float* zbuf   = w;
    float* h[3]   = { w + NF, w + 2 * NF, w + 3 * NF };
    float* stats  = w + 4 * NF;       // 3 * 256  (sum | sumsq per layer)
    float* ss     = stats + 768;      // 3 * 256  (scale | shift per layer)
    float* idaff  = ss + 768;         // 256      (identity scale | shift)
    float* g_feat = idaff + 256;      // 512 * 384
    int*   counts = (int*)(g_feat + (size_t)NGRAPH * 384);   // N
    int*   rowptr = counts + N;                              // N + 1
    int*   cursor = rowptr + N + 1;                          // N
    int*   csr    = cursor + N;                              // E

    k_setup<<<1, 256, 0, stream>>>(idaff, idaff + 128, stats);

    // ---- build CSR (once per call) ----
    hipMemsetAsync(counts, 0, (size_t)N * sizeof(int), stream);
    k_hist<<<(E + 255) / 256, 256, 0, stream>>>(dst, E, counts);
    k_scan<<<1, 1024, 0, stream>>>(counts, N, rowptr, cursor);
    k_scatter<<<(E + 255) / 256, 256, 0, stream>>>(src, dst, E, cursor, csr);

    for (int l = 0; l < NLAYERS; ++l) {
        const float* hin = (l == 0) ? x : h[l - 1];
        const float* asc = (l == 0) ? idaff : (ss + (l - 1) * 256);

        k_agg_csr<<<(N + 3) / 4, 256, 0, stream>>>(
            rowptr, csr, (const float2*)hin, asc, epsg, l, (float2*)zbuf, N);

        k_gin_mlp<<<(N + 63) / 64, 256, 0, stream>>>(
            zbuf, W1 + (size_t)l * HID * HID, b1 + l * HID,
            W2 + (size_t)l * HID * HID, b2 + l * HID,
            h[l], stats + l * 256, stats + l * 256 + 128, N);

        k_bn_fin<<<1, 128, 0, stream>>>(
            stats + l * 256, stats + l * 256 + 128, gamma, beta, l, N,
            ss + l * 256, ss + l * 256 + 128);
    }

    k_pool<<<NGRAPH, 384, 0, stream>>>(batch, N, h[0], h[1], h[2], ss, g_feat);
    k_mlp<<<NGRAPH, 128, 0, stream>>>(g_feat, l1w, l1b, l2w, l2b, (float*)d_out);
}

// Round 3
// 1130.867 us; speedup vs baseline: 7.6508x; 1.1982x over previous
//
#include <hip/hip_runtime.h>

#define HID 128
#define NGRAPH 512
#define NLAYERS 3
#define BN_EPS 1e-5f

// ---------------------------------------------------------------------------
// setup: identity affine (for layer 0) + zero BN stats
// ---------------------------------------------------------------------------
__global__ void k_setup(float* __restrict__ id_scale, float* __restrict__ id_shift,
                        float* __restrict__ stats) {
    int t = threadIdx.x;              // 256 threads
    if (t < 128) { id_scale[t] = 1.0f; id_shift[t] = 0.0f; }
    for (int l = 0; l < NLAYERS; ++l) stats[l * 256 + t] = 0.0f;  // sum[128]+sq[128] per layer
}

// ---------------------------------------------------------------------------
// CSR build: histogram of dst
// ---------------------------------------------------------------------------
__global__ void k_hist(const int* __restrict__ dst, int E, int* __restrict__ counts) {
    int i = blockIdx.x * blockDim.x + threadIdx.x;
    if (i < E) atomicAdd(&counts[dst[i]], 1);
}

// ---------------------------------------------------------------------------
// hierarchical exclusive scan: phase A — per-block (1024 elems) partial sums
// ---------------------------------------------------------------------------
__global__ __launch_bounds__(256) void k_bsum(const int* __restrict__ counts, int N,
                                              int* __restrict__ bsum) {
    __shared__ int red[256];
    int t = threadIdx.x;
    int base = blockIdx.x * 1024 + t * 4;
    int s = 0;
    if (base + 3 < N) {
        int4 v = *(const int4*)&counts[base];
        s = v.x + v.y + v.z + v.w;
    } else {
        for (int i = 0; i < 4; ++i) if (base + i < N) s += counts[base + i];
    }
    red[t] = s;
    __syncthreads();
    for (int off = 128; off > 0; off >>= 1) {
        if (t < off) red[t] += red[t + off];
        __syncthreads();
    }
    if (t == 0) bsum[blockIdx.x] = red[0];
}

// phase B — scan the (<=1024) block sums in one small block; write total to rowptrN
__global__ __launch_bounds__(128) void k_bscan(int* __restrict__ bsum, int nblk,
                                               int* __restrict__ rowptrN) {
    __shared__ int sh[1024];
    int t = threadIdx.x;
    for (int i = t; i < nblk; i += 128) sh[i] = bsum[i];
    __syncthreads();
    if (t == 0) {
        int run = 0;
        for (int i = 0; i < nblk; ++i) { int c = sh[i]; sh[i] = run; run += c; }
        *rowptrN = run;
    }
    __syncthreads();
    for (int i = t; i < nblk; i += 128) bsum[i] = sh[i];
}

// phase C — local exclusive scan + block offset; write rowptr & cursor
__global__ __launch_bounds__(256) void k_apply(const int* __restrict__ counts, int N,
                                               const int* __restrict__ bsum,
                                               int* __restrict__ rowptr, int* __restrict__ cursor) {
    __shared__ int tsum[256];
    int t = threadIdx.x;
    int base = blockIdx.x * 1024 + t * 4;
    int c[4] = {0, 0, 0, 0};
    if (base + 3 < N) {
        int4 v = *(const int4*)&counts[base];
        c[0] = v.x; c[1] = v.y; c[2] = v.z; c[3] = v.w;
    } else {
        for (int i = 0; i < 4; ++i) if (base + i < N) c[i] = counts[base + i];
    }
    int s = c[0] + c[1] + c[2] + c[3];
    tsum[t] = s;
    __syncthreads();
    for (int off = 1; off < 256; off <<= 1) {
        int v = (t >= off) ? tsum[t - off] : 0;
        __syncthreads();
        tsum[t] += v;
        __syncthreads();
    }
    int run = bsum[blockIdx.x] + ((t == 0) ? 0 : tsum[t - 1]);
    #pragma unroll
    for (int i = 0; i < 4; ++i) {
        if (base + i < N) { rowptr[base + i] = run; cursor[base + i] = run; run += c[i]; }
    }
}

__global__ void k_scatter(const int* __restrict__ src, const int* __restrict__ dst, int E,
                          int* __restrict__ cursor, int* __restrict__ csr_src) {
    int i = blockIdx.x * blockDim.x + threadIdx.x;
    if (i < E) {
        int pos = atomicAdd(&cursor[dst[i]], 1);
        csr_src[pos] = src[i];
    }
}

// ---------------------------------------------------------------------------
// CSR aggregation, fused with self term + folded BN affine of the INPUT:
//   z0[i] = sc * ((1+eps)*h_i + sum_{j->i} h_j) + (1+eps+deg)*sh
// one wave (64 lanes, float2 each) per node; 4 nodes per 256-block.
// ---------------------------------------------------------------------------
__global__ __launch_bounds__(256) void k_agg_csr(
        const int* __restrict__ rowptr, const int* __restrict__ csr_src,
        const float2* __restrict__ hin, const float* __restrict__ ss,
        const float* __restrict__ eps_gin, int layer, float2* __restrict__ z0, int N) {
    int node = blockIdx.x * 4 + (threadIdx.x >> 6);
    if (node >= N) return;
    int f = threadIdx.x & 63;                      // float2 lane
    float2 sc = ((const float2*)ss)[f];
    float2 sh = ((const float2*)(ss + HID))[f];
    float e1 = 1.0f + eps_gin[layer];
    int beg = rowptr[node], end = rowptr[node + 1];
    float2 hself = hin[(size_t)node * 64 + f];
    float sx = e1 * hself.x, sy = e1 * hself.y;
    int p = beg;
    for (; p + 3 < end; p += 4) {
        int s0 = csr_src[p], s1 = csr_src[p + 1], s2 = csr_src[p + 2], s3 = csr_src[p + 3];
        float2 v0 = hin[(size_t)s0 * 64 + f];
        float2 v1 = hin[(size_t)s1 * 64 + f];
        float2 v2 = hin[(size_t)s2 * 64 + f];
        float2 v3 = hin[(size_t)s3 * 64 + f];
        sx += (v0.x + v1.x) + (v2.x + v3.x);
        sy += (v0.y + v1.y) + (v2.y + v3.y);
    }
    for (; p < end; ++p) {
        int s0 = csr_src[p];
        float2 v0 = hin[(size_t)s0 * 64 + f];
        sx += v0.x; sy += v0.y;
    }
    float c = e1 + (float)(end - beg);
    float2 r;
    r.x = sc.x * sx + c * sh.x;
    r.y = sc.y * sy + c * sh.y;
    z0[(size_t)node * 64 + f] = r;
}

// ---------------------------------------------------------------------------
// fused per-layer MLP: h_out = relu(relu(z0@W1+b1)@W2+b2), + BN stats (sum, sumsq)
// Block: 256 threads, 64 rows. LDS: A-tile (xor-swizzled) 32KB + W k-chunk 32KB.
// z1 never leaves LDS. Thread micro-tile: 4 rows x 8 cols.
// ---------------------------------------------------------------------------
__global__ __launch_bounds__(256) void k_gin_mlp(
        const float* __restrict__ A, const float* __restrict__ W1, const float* __restrict__ b1,
        const float* __restrict__ W2, const float* __restrict__ b2,
        float* __restrict__ Hout, float* __restrict__ stat_sum, float* __restrict__ stat_sq, int N) {
    __shared__ float As[64][128];   // As[r][k ^ ((r&3)*8)] = A[row0+r][k]
    __shared__ float Ws[64][128];   // one 64-row k-chunk of W

    const int t = threadIdx.x;
    const int row0 = blockIdx.x * 64;
    int valid = N - row0; if (valid > 64) valid = 64;

    // ---- stage A tile (swizzled) ----
    {
        const float4* A4 = (const float4*)A;
        #pragma unroll
        for (int i = 0; i < 8; ++i) {
            int idx4 = t + i * 256;          // 0..2047
            int r = idx4 >> 5;               // 0..63
            int k4 = idx4 & 31;              // float4 col
            float4 v = make_float4(0.f, 0.f, 0.f, 0.f);
            if (r < valid) v = A4[(size_t)(row0 + r) * 32 + k4];
            int kx = (k4 * 4) ^ ((r & 3) * 8);
            *(float4*)&As[r][kx] = v;
        }
    }

    const int rg = t >> 4;           // 0..15
    const int cg = t & 15;           // 0..15
    const int r0 = rg * 4;
    const int c0 = cg * 8;

    float acc[4][8];
    #pragma unroll
    for (int i = 0; i < 4; ++i)
        #pragma unroll
        for (int j = 0; j < 8; ++j) acc[i][j] = 0.f;

    // ---- GEMM1: z1 = z0 @ W1 (k in two 64-chunks) ----
    for (int ch = 0; ch < 2; ++ch) {
        __syncthreads();
        const float4* W4 = (const float4*)(W1 + (size_t)ch * 64 * HID);
        #pragma unroll
        for (int i = 0; i < 8; ++i) {
            int idx4 = t + i * 256;
            *(float4*)&Ws[idx4 >> 5][(idx4 & 31) * 4] = W4[idx4];
        }
        __syncthreads();
        for (int k = 0; k < 64; ++k) {
            int kk = ch * 64 + k;
            float a[4];
            #pragma unroll
            for (int i = 0; i < 4; ++i) a[i] = As[r0 + i][kk ^ (i * 8)];
            float w[8];
            *(float4*)&w[0] = *(const float4*)&Ws[k][c0];
            *(float4*)&w[4] = *(const float4*)&Ws[k][c0 + 4];
            #pragma unroll
            for (int i = 0; i < 4; ++i)
                #pragma unroll
                for (int j = 0; j < 8; ++j) acc[i][j] = fmaf(a[i], w[j], acc[i][j]);
        }
    }

    // ---- bias+relu, z1 tile back into As (same swizzle) ----
    float bv[8];
    *(float4*)&bv[0] = *(const float4*)&b1[c0];
    *(float4*)&bv[4] = *(const float4*)&b1[c0 + 4];
    __syncthreads();   // all As(z0) reads done
    #pragma unroll
    for (int i = 0; i < 4; ++i) {
        int r = r0 + i;
        float z[8];
        #pragma unroll
        for (int j = 0; j < 8; ++j) z[j] = fmaxf(acc[i][j] + bv[j], 0.f);
        int swz = i * 8;   // (r&3)*8
        *(float4*)&As[r][c0 ^ swz]       = *(float4*)&z[0];
        *(float4*)&As[r][(c0 + 4) ^ swz] = *(float4*)&z[4];
    }
    #pragma unroll
    for (int i = 0; i < 4; ++i)
        #pragma unroll
        for (int j = 0; j < 8; ++j) acc[i][j] = 0.f;

    // ---- GEMM2: z2 = z1 @ W2 ----
    for (int ch = 0; ch < 2; ++ch) {
        __syncthreads();
        const float4* W4 = (const float4*)(W2 + (size_t)ch * 64 * HID);
        #pragma unroll
        for (int i = 0; i < 8; ++i) {
            int idx4 = t + i * 256;
            *(float4*)&Ws[idx4 >> 5][(idx4 & 31) * 4] = W4[idx4];
        }
        __syncthreads();
        for (int k = 0; k < 64; ++k) {
            int kk = ch * 64 + k;
            float a[4];
            #pragma unroll
            for (int i = 0; i < 4; ++i) a[i] = As[r0 + i][kk ^ (i * 8)];
            float w[8];
            *(float4*)&w[0] = *(const float4*)&Ws[k][c0];
            *(float4*)&w[4] = *(const float4*)&Ws[k][c0 + 4];
            #pragma unroll
            for (int i = 0; i < 4; ++i)
                #pragma unroll
                for (int j = 0; j < 8; ++j) acc[i][j] = fmaf(a[i], w[j], acc[i][j]);
        }
    }

    // ---- epilogue: bias+relu, write h, BN partial stats ----
    float bv2[8];
    *(float4*)&bv2[0] = *(const float4*)&b2[c0];
    *(float4*)&bv2[4] = *(const float4*)&b2[c0 + 4];
    float csum[8], csq[8];
    #pragma unroll
    for (int j = 0; j < 8; ++j) { csum[j] = 0.f; csq[j] = 0.f; }
    #pragma unroll
    for (int i = 0; i < 4; ++i) {
        int grow = row0 + r0 + i;
        if (grow < N) {
            float z[8];
            #pragma unroll
            for (int j = 0; j < 8; ++j) {
                z[j] = fmaxf(acc[i][j] + bv2[j], 0.f);
                csum[j] += z[j];
                csq[j]  += z[j] * z[j];
            }
            *(float4*)&Hout[(size_t)grow * HID + c0]     = *(float4*)&z[0];
            *(float4*)&Hout[(size_t)grow * HID + c0 + 4] = *(float4*)&z[4];
        }
    }
    // deterministic block reduction via LDS (reuse As rows)
    __syncthreads();   // all As(z1) reads done
    #pragma unroll
    for (int j = 0; j < 8; ++j) {
        As[rg][c0 + j]      = csum[j];
        As[16 + rg][c0 + j] = csq[j];
    }
    __syncthreads();
    if (t < 128) {
        float s = 0.f, q = 0.f;
        #pragma unroll
        for (int g = 0; g < 16; ++g) { s += As[g][t]; q += As[16 + g][t]; }
        unsafeAtomicAdd(&stat_sum[t], s);
        unsafeAtomicAdd(&stat_sq[t], q);
    }
}

// ---------------------------------------------------------------------------
// fold BN into per-feature scale/shift
// ---------------------------------------------------------------------------
__global__ void k_bn_fin(const float* __restrict__ stat_sum, const float* __restrict__ stat_sq,
                         const float* __restrict__ gamma, const float* __restrict__ beta,
                         int layer, int N, float* __restrict__ scale, float* __restrict__ shift) {
    int f = threadIdx.x;   // 128
    float invn = 1.0f / (float)N;
    float mu = stat_sum[f] * invn;
    float var = stat_sq[f] * invn - mu * mu;
    float inv = rsqrtf(var + BN_EPS);
    float sc = gamma[layer * HID + f] * inv;
    scale[f] = sc;
    shift[f] = beta[layer * HID + f] - mu * sc;
}

// ---------------------------------------------------------------------------
// global mean pool over concat(h0,h1,h2) with BN affine folded out of the loop
// ---------------------------------------------------------------------------
__global__ __launch_bounds__(384) void k_pool(const int* __restrict__ batch, int N,
                       const float* __restrict__ h0, const float* __restrict__ h1,
                       const float* __restrict__ h2, const float* __restrict__ ss,
                       float* __restrict__ g_feat) {
    int g = blockIdx.x;
    int f = threadIdx.x;            // 0..383
    int start, end;
    { int lo = 0, hi = N; while (lo < hi) { int m = (lo + hi) >> 1; if (batch[m] < g) lo = m + 1; else hi = m; } start = lo; }
    { int lo = start, hi = N; while (lo < hi) { int m = (lo + hi) >> 1; if (batch[m] < g + 1) lo = m + 1; else hi = m; } end = lo; }
    int l = f >> 7, c = f & 127;
    const float* hb = (l == 0) ? h0 : (l == 1) ? h1 : h2;
    float sc = ss[l * 256 + c];
    float sh = ss[l * 256 + 128 + c];
    float sum = 0.f;
    for (int i = start; i < end; ++i) sum += hb[(size_t)i * HID + c];
    float cnt = (float)(end - start);
    g_feat[g * 384 + f] = (sum * sc + sh * cnt) / fmaxf(cnt, 1.0f);
}

// ---------------------------------------------------------------------------
// final MLP: out = relu(g_feat @ lin1 + b1) @ lin2 + b2 ; one block per graph
// ---------------------------------------------------------------------------
__global__ __launch_bounds__(128) void k_mlp(const float* __restrict__ g_feat,
                     const float* __restrict__ w1, const float* __restrict__ b1,
                     const float* __restrict__ w2, const float* __restrict__ b2,
                     float* __restrict__ out) {
    __shared__ float gl[384];
    __shared__ float hh[128];
    int g = blockIdx.x, t = threadIdx.x;   // 128 threads
    for (int i = t; i < 384; i += 128) gl[i] = g_feat[g * 384 + i];
    __syncthreads();
    float acc = b1[t];
    for (int k = 0; k < 384; ++k) acc = fmaf(gl[k], w1[k * HID + t], acc);
    hh[t] = fmaxf(acc, 0.f);
    __syncthreads();
    if (t < 10) {
        float a2 = b2[t];
        for (int k = 0; k < 128; ++k) a2 = fmaf(hh[k], w2[k * 10 + t], a2);
        out[g * 10 + t] = a2;
    }
}

// ---------------------------------------------------------------------------
extern "C" void kernel_launch(void* const* d_in, const int* in_sizes, int n_in,
                              void* d_out, int out_size, void* d_ws, size_t ws_size,
                              hipStream_t stream) {
    const float* x     = (const float*)d_in[0];
    const int*   ei    = (const int*)d_in[1];
    const int*   batch = (const int*)d_in[2];
    const float* W1    = (const float*)d_in[3];
    const float* b1    = (const float*)d_in[4];
    const float* W2    = (const float*)d_in[5];
    const float* b2    = (const float*)d_in[6];
    const float* gamma = (const float*)d_in[7];
    const float* beta  = (const float*)d_in[8];
    const float* epsg  = (const float*)d_in[9];
    const float* l1w   = (const float*)d_in[10];
    const float* l1b   = (const float*)d_in[11];
    const float* l2w   = (const float*)d_in[12];
    const float* l2b   = (const float*)d_in[13];

    const int N = in_sizes[0] / HID;
    const int E = in_sizes[1] / 2;
    const int* src = ei;
    const int* dst = ei + E;

    float* w = (float*)d_ws;
    const size_t NF = (size_t)N * HID;
    float* zbuf   = w;
    float* h[3]   = { w + NF, w + 2 * NF, w + 3 * NF };
    float* stats  = w + 4 * NF;       // 3 * 256  (sum | sumsq per layer)
    float* ss     = stats + 768;      // 3 * 256  (scale | shift per layer)
    float* idaff  = ss + 768;         // 256      (identity scale | shift)
    float* g_feat = idaff + 256;      // 512 * 384
    int*   counts = (int*)(g_feat + (size_t)NGRAPH * 384);   // N
    int*   rowptr = counts + N;                              // N + 1
    int*   cursor = rowptr + N + 1;                          // N
    int*   csr    = cursor + N;                              // E
    int*   bsum   = csr + E;                                 // <= 1024

    k_setup<<<1, 256, 0, stream>>>(idaff, idaff + 128, stats);

    // ---- build CSR (once per call) ----
    hipMemsetAsync(counts, 0, (size_t)N * sizeof(int), stream);
    k_hist<<<(E + 255) / 256, 256, 0, stream>>>(dst, E, counts);
    int nblk = (N + 1023) / 1024;
    k_bsum<<<nblk, 256, 0, stream>>>(counts, N, bsum);
    k_bscan<<<1, 128, 0, stream>>>(bsum, nblk, rowptr + N);
    k_apply<<<nblk, 256, 0, stream>>>(counts, N, bsum, rowptr, cursor);
    k_scatter<<<(E + 255) / 256, 256, 0, stream>>>(src, dst, E, cursor, csr);

    for (int l = 0; l < NLAYERS; ++l) {
        const float* hin = (l == 0) ? x : h[l - 1];
        const float* asc = (l == 0) ? idaff : (ss + (l - 1) * 256);

        k_agg_csr<<<(N + 3) / 4, 256, 0, stream>>>(
            rowptr, csr, (const float2*)hin, asc, epsg, l, (float2*)zbuf, N);

        k_gin_mlp<<<(N + 63) / 64, 256, 0, stream>>>(
            zbuf, W1 + (size_t)l * HID * HID, b1 + l * HID,
            W2 + (size_t)l * HID * HID, b2 + l * HID,
            h[l], stats + l * 256, stats + l * 256 + 128, N);

        k_bn_fin<<<1, 128, 0, stream>>>(
            stats + l * 256, stats + l * 256 + 128, gamma, beta, l, N,
            ss + l * 256, ss + l * 256 + 128);
    }

    k_pool<<<NGRAPH, 384, 0, stream>>>(batch, N, h[0], h[1], h[2], ss, g_feat);
    k_mlp<<<NGRAPH, 128, 0, stream>>>(g_feat, l1w, l1b, l2w, l2b, (float*)d_out);
}

// Round 4
// 953.093 us; speedup vs baseline: 9.0779x; 1.1865x over previous
//
#include <hip/hip_runtime.h>

#define HID 128
#define NGRAPH 512
#define NLAYERS 3
#define BN_EPS 1e-5f

typedef __attribute__((ext_vector_type(8))) short bf16x8;
typedef __attribute__((ext_vector_type(4))) float f32x4;

__device__ inline unsigned short f2bf(float x) {
    union { float f; unsigned u; } v; v.f = x;
    unsigned r = v.u + 0x7FFFu + ((v.u >> 16) & 1u);
    return (unsigned short)(r >> 16);
}
__device__ inline float bf2f(unsigned short b) {
    union { float f; unsigned u; } v; v.u = ((unsigned)b) << 16; return v.f;
}

// ---------------------------------------------------------------------------
// setup: identity affine (for layer 0) + zero BN stats
// ---------------------------------------------------------------------------
__global__ void k_setup(float* __restrict__ id_scale, float* __restrict__ id_shift,
                        float* __restrict__ stats) {
    int t = threadIdx.x;              // 256 threads
    if (t < 128) { id_scale[t] = 1.0f; id_shift[t] = 0.0f; }
    for (int l = 0; l < NLAYERS; ++l) stats[l * 256 + t] = 0.0f;
}

// ---------------------------------------------------------------------------
// W convert+transpose: Wt[l][n][k] = split_bf16(W[l][k][n]); run once per call
// ---------------------------------------------------------------------------
__global__ void k_wconv(const float* __restrict__ W, ushort* __restrict__ Wth,
                        ushort* __restrict__ Wtl, int total) {
    int e = blockIdx.x * 256 + threadIdx.x;
    if (e >= total) return;
    int l = e >> 14, rem = e & 16383, k = rem >> 7, n = rem & 127;
    float v = W[e];
    ushort hi = f2bf(v);
    ushort lo = f2bf(v - bf2f(hi));
    int o = (l << 14) + (n << 7) + k;
    Wth[o] = hi; Wtl[o] = lo;
}

// ---------------------------------------------------------------------------
// CSR build
// ---------------------------------------------------------------------------
__global__ void k_hist(const int* __restrict__ dst, int E, int* __restrict__ counts) {
    int i = blockIdx.x * blockDim.x + threadIdx.x;
    if (i < E) atomicAdd(&counts[dst[i]], 1);
}

__global__ __launch_bounds__(256) void k_bsum(const int* __restrict__ counts, int N,
                                              int* __restrict__ bsum) {
    __shared__ int red[256];
    int t = threadIdx.x;
    int base = blockIdx.x * 1024 + t * 4;
    int s = 0;
    if (base + 3 < N) {
        int4 v = *(const int4*)&counts[base];
        s = v.x + v.y + v.z + v.w;
    } else {
        for (int i = 0; i < 4; ++i) if (base + i < N) s += counts[base + i];
    }
    red[t] = s;
    __syncthreads();
    for (int off = 128; off > 0; off >>= 1) {
        if (t < off) red[t] += red[t + off];
        __syncthreads();
    }
    if (t == 0) bsum[blockIdx.x] = red[0];
}

__global__ __launch_bounds__(128) void k_bscan(int* __restrict__ bsum, int nblk,
                                               int* __restrict__ rowptrN) {
    __shared__ int sh[1024];
    int t = threadIdx.x;
    for (int i = t; i < nblk; i += 128) sh[i] = bsum[i];
    __syncthreads();
    if (t == 0) {
        int run = 0;
        for (int i = 0; i < nblk; ++i) { int c = sh[i]; sh[i] = run; run += c; }
        *rowptrN = run;
    }
    __syncthreads();
    for (int i = t; i < nblk; i += 128) bsum[i] = sh[i];
}

__global__ __launch_bounds__(256) void k_apply(const int* __restrict__ counts, int N,
                                               const int* __restrict__ bsum,
                                               int* __restrict__ rowptr, int* __restrict__ cursor) {
    __shared__ int tsum[256];
    int t = threadIdx.x;
    int base = blockIdx.x * 1024 + t * 4;
    int c[4] = {0, 0, 0, 0};
    if (base + 3 < N) {
        int4 v = *(const int4*)&counts[base];
        c[0] = v.x; c[1] = v.y; c[2] = v.z; c[3] = v.w;
    } else {
        for (int i = 0; i < 4; ++i) if (base + i < N) c[i] = counts[base + i];
    }
    int s = c[0] + c[1] + c[2] + c[3];
    tsum[t] = s;
    __syncthreads();
    for (int off = 1; off < 256; off <<= 1) {
        int v = (t >= off) ? tsum[t - off] : 0;
        __syncthreads();
        tsum[t] += v;
        __syncthreads();
    }
    int run = bsum[blockIdx.x] + ((t == 0) ? 0 : tsum[t - 1]);
    #pragma unroll
    for (int i = 0; i < 4; ++i) {
        if (base + i < N) { rowptr[base + i] = run; cursor[base + i] = run; run += c[i]; }
    }
}

__global__ void k_scatter(const int* __restrict__ src, const int* __restrict__ dst, int E,
                          int* __restrict__ cursor, int* __restrict__ csr_src) {
    int i = blockIdx.x * blockDim.x + threadIdx.x;
    if (i < E) {
        int pos = atomicAdd(&cursor[dst[i]], 1);
        csr_src[pos] = src[i];
    }
}

// ---------------------------------------------------------------------------
// CSR aggregation + folded input affine; emits z0 as bf16 hi/lo pair.
//   z0[i] = sc * ((1+eps)*h_i + sum_{j->i} h_j) + (1+eps+deg)*sh
// ---------------------------------------------------------------------------
__global__ __launch_bounds__(256) void k_agg_csr(
        const int* __restrict__ rowptr, const int* __restrict__ csr_src,
        const float2* __restrict__ hin, const float* __restrict__ ss,
        const float* __restrict__ eps_gin, int layer,
        ushort* __restrict__ z0h, ushort* __restrict__ z0l, int N) {
    int node = blockIdx.x * 4 + (threadIdx.x >> 6);
    if (node >= N) return;
    int f = threadIdx.x & 63;                      // float2 lane
    float2 sc = ((const float2*)ss)[f];
    float2 sh = ((const float2*)(ss + HID))[f];
    float e1 = 1.0f + eps_gin[layer];
    int beg = rowptr[node], end = rowptr[node + 1];
    float2 hself = hin[(size_t)node * 64 + f];
    float sx = e1 * hself.x, sy = e1 * hself.y;
    int p = beg;
    for (; p + 3 < end; p += 4) {
        int s0 = csr_src[p], s1 = csr_src[p + 1], s2 = csr_src[p + 2], s3 = csr_src[p + 3];
        float2 v0 = hin[(size_t)s0 * 64 + f];
        float2 v1 = hin[(size_t)s1 * 64 + f];
        float2 v2 = hin[(size_t)s2 * 64 + f];
        float2 v3 = hin[(size_t)s3 * 64 + f];
        sx += (v0.x + v1.x) + (v2.x + v3.x);
        sy += (v0.y + v1.y) + (v2.y + v3.y);
    }
    for (; p < end; ++p) {
        int s0 = csr_src[p];
        float2 v0 = hin[(size_t)s0 * 64 + f];
        sx += v0.x; sy += v0.y;
    }
    float c = e1 + (float)(end - beg);
    float rx = sc.x * sx + c * sh.x;
    float ry = sc.y * sy + c * sh.y;
    ushort hx = f2bf(rx); ushort lx = f2bf(rx - bf2f(hx));
    ushort hy = f2bf(ry); ushort ly = f2bf(ry - bf2f(hy));
    ((unsigned*)z0h)[(size_t)node * 64 + f] = ((unsigned)hy << 16) | hx;
    ((unsigned*)z0l)[(size_t)node * 64 + f] = ((unsigned)ly << 16) | lx;
}

// ---------------------------------------------------------------------------
// fused per-layer MLP via MFMA, bf16x3 split (fp32-grade accuracy):
//   h_out = relu(relu(z0@W1+b1)@W2+b2), + BN stats
// Block: 256 thr = 4 waves; tile 64 rows x 128 cols; wave owns 32 cols.
// LDS 64KB: W chunk [128n][32d] hi+lo (32KB) | A/z1 region (32KB).
// XOR swizzle (4-dword granularity, keyed by row&7) -> conflict-free b128.
// ---------------------------------------------------------------------------
__global__ __launch_bounds__(256) void k_gin_mlp(
        const ushort* __restrict__ z0h, const ushort* __restrict__ z0l,
        const ushort* __restrict__ w1h, const ushort* __restrict__ w1l,
        const float* __restrict__ b1,
        const ushort* __restrict__ w2h, const ushort* __restrict__ w2l,
        const float* __restrict__ b2,
        float* __restrict__ Hout, float* __restrict__ stat_sum, float* __restrict__ stat_sq,
        int N) {
    __shared__ __align__(16) ushort smem[32768];   // 64 KB
    uint4* s4 = (uint4*)smem;
    // uint4 regions: Wh 0..1023 | Wl 1024..2047 | Ah 2048..2559 | Al 2560..3071
    // z1 overlay:    Zh 2048..3071 (us 16384)   | Zl 3072..4095 (us 24576)

    const int t = threadIdx.x;
    const int lane = t & 63;
    const int wv = t >> 6;
    const int li = lane & 15;
    const int kq = lane >> 4;
    const int n0 = wv * 32;
    const int row0 = blockIdx.x * 64;
    const int swz = (li & 7) * 4;      // fragment-read xor (row&7 == li&7 for all tiles)

    const int sr = t >> 3;             // staging: row 0..31 per pass
    const int sl = t & 7;              // staging: 4-dword column

    f32x4 acc[4][2];
    #pragma unroll
    for (int i = 0; i < 4; ++i) {
        acc[i][0] = (f32x4){0.f, 0.f, 0.f, 0.f};
        acc[i][1] = (f32x4){0.f, 0.f, 0.f, 0.f};
    }

    // ---------------- GEMM1: z1 = z0 @ W1 ----------------
    for (int ch = 0; ch < 2; ++ch) {
        __syncthreads();
        #pragma unroll
        for (int i = 0; i < 2; ++i) {           // A chunk: 64 rows x 8 uint4
            int r = sr + i * 32;
            int gi = (row0 + r) * 16 + ch * 8 + sl;
            uint4 vh = make_uint4(0, 0, 0, 0), vl = vh;
            if (row0 + r < N) { vh = ((const uint4*)z0h)[gi]; vl = ((const uint4*)z0l)[gi]; }
            int d = r * 8 + (sl ^ (r & 7));
            s4[2048 + d] = vh;
            s4[2560 + d] = vl;
        }
        #pragma unroll
        for (int i = 0; i < 4; ++i) {           // W chunk: 128 rows x 8 uint4
            int n = sr + i * 32;
            int gi = n * 16 + ch * 8 + sl;
            int d = n * 8 + (sl ^ (n & 7));
            s4[d]        = ((const uint4*)w1h)[gi];
            s4[1024 + d] = ((const uint4*)w1l)[gi];
        }
        __syncthreads();
        #pragma unroll
        for (int ks = 0; ks < 2; ++ks) {
            int aoff = (ks * 16 + kq * 4) ^ swz;
            bf16x8 ah[4], al[4], bh[2], bl[2];
            #pragma unroll
            for (int mt = 0; mt < 4; ++mt) {
                int idx = ((mt * 16 + li) * 32 + aoff) * 2;
                ah[mt] = *(const bf16x8*)&smem[16384 + idx];
                al[mt] = *(const bf16x8*)&smem[20480 + idx];
            }
            #pragma unroll
            for (int nt = 0; nt < 2; ++nt) {
                int idx = ((n0 + nt * 16 + li) * 32 + aoff) * 2;
                bh[nt] = *(const bf16x8*)&smem[idx];
                bl[nt] = *(const bf16x8*)&smem[8192 + idx];
            }
            #pragma unroll
            for (int mt = 0; mt < 4; ++mt)
                #pragma unroll
                for (int nt = 0; nt < 2; ++nt) {
                    acc[mt][nt] = __builtin_amdgcn_mfma_f32_16x16x32_bf16(ah[mt], bh[nt], acc[mt][nt], 0, 0, 0);
                    acc[mt][nt] = __builtin_amdgcn_mfma_f32_16x16x32_bf16(ah[mt], bl[nt], acc[mt][nt], 0, 0, 0);
                    acc[mt][nt] = __builtin_amdgcn_mfma_f32_16x16x32_bf16(al[mt], bh[nt], acc[mt][nt], 0, 0, 0);
                }
        }
    }

    // ---- z1 = relu(acc + b1) -> Z region (A-layout, bf16 hi/lo, swizzled) ----
    float bz0 = b1[n0 + li], bz1 = b1[n0 + 16 + li];
    __syncthreads();                    // all GEMM1 LDS reads done before overwrite
    #pragma unroll
    for (int mt = 0; mt < 4; ++mt) {
        #pragma unroll
        for (int nt = 0; nt < 2; ++nt) {
            int c = n0 + nt * 16 + li;
            int dk = c >> 1;
            int halfbase = (dk >> 5) * 32;
            int dlow = dk & 31;
            int codd = c & 1;
            float bias = nt ? bz1 : bz0;
            #pragma unroll
            for (int reg = 0; reg < 4; ++reg) {
                int r = mt * 16 + kq * 4 + reg;
                float v = fmaxf(acc[mt][nt][reg] + bias, 0.f);
                ushort hi = f2bf(v);
                ushort lo = f2bf(v - bf2f(hi));
                int us = (r * 64 + halfbase + (dlow ^ ((r & 7) * 4))) * 2 + codd;
                smem[16384 + us] = hi;
                smem[24576 + us] = lo;
            }
        }
    }
    #pragma unroll
    for (int i = 0; i < 4; ++i) {
        acc[i][0] = (f32x4){0.f, 0.f, 0.f, 0.f};
        acc[i][1] = (f32x4){0.f, 0.f, 0.f, 0.f};
    }

    // ---------------- GEMM2: z2 = z1 @ W2 ----------------
    for (int ch = 0; ch < 2; ++ch) {
        __syncthreads();                // ch0: z1 writes visible; ch1: W2(0) reads done
        #pragma unroll
        for (int i = 0; i < 4; ++i) {
            int n = sr + i * 32;
            int gi = n * 16 + ch * 8 + sl;
            int d = n * 8 + (sl ^ (n & 7));
            s4[d]        = ((const uint4*)w2h)[gi];
            s4[1024 + d] = ((const uint4*)w2l)[gi];
        }
        __syncthreads();
        #pragma unroll
        for (int ks = 0; ks < 2; ++ks) {
            int aoff = (ks * 16 + kq * 4) ^ swz;
            bf16x8 ah[4], al[4], bh[2], bl[2];
            #pragma unroll
            for (int mt = 0; mt < 4; ++mt) {
                int idx = ((mt * 16 + li) * 64 + ch * 32 + aoff) * 2;
                ah[mt] = *(const bf16x8*)&smem[16384 + idx];
                al[mt] = *(const bf16x8*)&smem[24576 + idx];
            }
            #pragma unroll
            for (int nt = 0; nt < 2; ++nt) {
                int idx = ((n0 + nt * 16 + li) * 32 + aoff) * 2;
                bh[nt] = *(const bf16x8*)&smem[idx];
                bl[nt] = *(const bf16x8*)&smem[8192 + idx];
            }
            #pragma unroll
            for (int mt = 0; mt < 4; ++mt)
                #pragma unroll
                for (int nt = 0; nt < 2; ++nt) {
                    acc[mt][nt] = __builtin_amdgcn_mfma_f32_16x16x32_bf16(ah[mt], bh[nt], acc[mt][nt], 0, 0, 0);
                    acc[mt][nt] = __builtin_amdgcn_mfma_f32_16x16x32_bf16(ah[mt], bl[nt], acc[mt][nt], 0, 0, 0);
                    acc[mt][nt] = __builtin_amdgcn_mfma_f32_16x16x32_bf16(al[mt], bh[nt], acc[mt][nt], 0, 0, 0);
                }
        }
    }

    // ---- epilogue: bias+relu, store h, BN stats (shuffle-reduce over quads) ----
    float bb0 = b2[n0 + li], bb1 = b2[n0 + 16 + li];
    float s0 = 0.f, q0 = 0.f, s1 = 0.f, q1 = 0.f;
    #pragma unroll
    for (int mt = 0; mt < 4; ++mt) {
        #pragma unroll
        for (int reg = 0; reg < 4; ++reg) {
            int grow = row0 + mt * 16 + kq * 4 + reg;
            if (grow < N) {
                float v0 = fmaxf(acc[mt][0][reg] + bb0, 0.f);
                float v1 = fmaxf(acc[mt][1][reg] + bb1, 0.f);
                Hout[(size_t)grow * HID + n0 + li]      = v0;
                Hout[(size_t)grow * HID + n0 + 16 + li] = v1;
                s0 += v0; q0 += v0 * v0; s1 += v1; q1 += v1 * v1;
            }
        }
    }
    s0 += __shfl_xor(s0, 16); s0 += __shfl_xor(s0, 32);
    q0 += __shfl_xor(q0, 16); q0 += __shfl_xor(q0, 32);
    s1 += __shfl_xor(s1, 16); s1 += __shfl_xor(s1, 32);
    q1 += __shfl_xor(q1, 16); q1 += __shfl_xor(q1, 32);
    if (kq == 0) {
        unsafeAtomicAdd(&stat_sum[n0 + li], s0);
        unsafeAtomicAdd(&stat_sq[n0 + li], q0);
        unsafeAtomicAdd(&stat_sum[n0 + 16 + li], s1);
        unsafeAtomicAdd(&stat_sq[n0 + 16 + li], q1);
    }
}

// ---------------------------------------------------------------------------
// fold BN into per-feature scale/shift
// ---------------------------------------------------------------------------
__global__ void k_bn_fin(const float* __restrict__ stat_sum, const float* __restrict__ stat_sq,
                         const float* __restrict__ gamma, const float* __restrict__ beta,
                         int layer, int N, float* __restrict__ scale, float* __restrict__ shift) {
    int f = threadIdx.x;   // 128
    float invn = 1.0f / (float)N;
    float mu = stat_sum[f] * invn;
    float var = stat_sq[f] * invn - mu * mu;
    float inv = rsqrtf(var + BN_EPS);
    float sc = gamma[layer * HID + f] * inv;
    scale[f] = sc;
    shift[f] = beta[layer * HID + f] - mu * sc;
}

// ---------------------------------------------------------------------------
// global mean pool over concat(h0,h1,h2) with BN affine folded out of the loop
// ---------------------------------------------------------------------------
__global__ __launch_bounds__(384) void k_pool(const int* __restrict__ batch, int N,
                       const float* __restrict__ h0, const float* __restrict__ h1,
                       const float* __restrict__ h2, const float* __restrict__ ss,
                       float* __restrict__ g_feat) {
    int g = blockIdx.x;
    int f = threadIdx.x;            // 0..383
    int start, end;
    { int lo = 0, hi = N; while (lo < hi) { int m = (lo + hi) >> 1; if (batch[m] < g) lo = m + 1; else hi = m; } start = lo; }
    { int lo = start, hi = N; while (lo < hi) { int m = (lo + hi) >> 1; if (batch[m] < g + 1) lo = m + 1; else hi = m; } end = lo; }
    int l = f >> 7, c = f & 127;
    const float* hb = (l == 0) ? h0 : (l == 1) ? h1 : h2;
    float sc = ss[l * 256 + c];
    float sh = ss[l * 256 + 128 + c];
    float sum = 0.f;
    for (int i = start; i < end; ++i) sum += hb[(size_t)i * HID + c];
    float cnt = (float)(end - start);
    g_feat[g * 384 + f] = (sum * sc + sh * cnt) / fmaxf(cnt, 1.0f);
}

// ---------------------------------------------------------------------------
// final MLP
// ---------------------------------------------------------------------------
__global__ __launch_bounds__(128) void k_mlp(const float* __restrict__ g_feat,
                     const float* __restrict__ w1, const float* __restrict__ b1,
                     const float* __restrict__ w2, const float* __restrict__ b2,
                     float* __restrict__ out) {
    __shared__ float gl[384];
    __shared__ float hh[128];
    int g = blockIdx.x, t = threadIdx.x;   // 128 threads
    for (int i = t; i < 384; i += 128) gl[i] = g_feat[g * 384 + i];
    __syncthreads();
    float acc = b1[t];
    for (int k = 0; k < 384; ++k) acc = fmaf(gl[k], w1[k * HID + t], acc);
    hh[t] = fmaxf(acc, 0.f);
    __syncthreads();
    if (t < 10) {
        float a2 = b2[t];
        for (int k = 0; k < 128; ++k) a2 = fmaf(hh[k], w2[k * 10 + t], a2);
        out[g * 10 + t] = a2;
    }
}

// ---------------------------------------------------------------------------
extern "C" void kernel_launch(void* const* d_in, const int* in_sizes, int n_in,
                              void* d_out, int out_size, void* d_ws, size_t ws_size,
                              hipStream_t stream) {
    const float* x     = (const float*)d_in[0];
    const int*   ei    = (const int*)d_in[1];
    const int*   batch = (const int*)d_in[2];
    const float* W1    = (const float*)d_in[3];
    const float* b1    = (const float*)d_in[4];
    const float* W2    = (const float*)d_in[5];
    const float* b2    = (const float*)d_in[6];
    const float* gamma = (const float*)d_in[7];
    const float* beta  = (const float*)d_in[8];
    const float* epsg  = (const float*)d_in[9];
    const float* l1w   = (const float*)d_in[10];
    const float* l1b   = (const float*)d_in[11];
    const float* l2w   = (const float*)d_in[12];
    const float* l2b   = (const float*)d_in[13];

    const int N = in_sizes[0] / HID;
    const int E = in_sizes[1] / 2;
    const int* src = ei;
    const int* dst = ei + E;

    float* w = (float*)d_ws;
    const size_t NF = (size_t)N * HID;
    float* zbuf   = w;                                       // hosts z0 hi/lo (NF floats worth)
    float* h[3]   = { w + NF, w + 2 * NF, w + 3 * NF };
    float* stats  = w + 4 * NF;       // 3 * 256
    float* ss     = stats + 768;      // 3 * 256
    float* idaff  = ss + 768;         // 256
    float* g_feat = idaff + 256;      // 512 * 384
    int*   counts = (int*)(g_feat + (size_t)NGRAPH * 384);   // N
    int*   rowptr = counts + N;                              // N + 1
    int*   cursor = rowptr + N + 1;                          // N (reused for W tables after scatter)
    int*   csr    = cursor + N;                              // E
    int*   bsum   = csr + E;                                 // <= 1024

    ushort* z0h = (ushort*)zbuf;          // NF ushorts
    ushort* z0l = z0h + NF;               // NF ushorts
    // W tables overlay the dead cursor buffer (384KB needed <= 400KB), 16B-aligned
    ushort* wt  = (ushort*)(((uintptr_t)cursor + 15) & ~(uintptr_t)15);
    ushort* w1h = wt;
    ushort* w1l = wt + 49152;
    ushort* w2h = wt + 98304;
    ushort* w2l = wt + 147456;

    k_setup<<<1, 256, 0, stream>>>(idaff, idaff + 128, stats);

    // ---- build CSR ----
    hipMemsetAsync(counts, 0, (size_t)N * sizeof(int), stream);
    k_hist<<<(E + 255) / 256, 256, 0, stream>>>(dst, E, counts);
    int nblk = (N + 1023) / 1024;
    k_bsum<<<nblk, 256, 0, stream>>>(counts, N, bsum);
    k_bscan<<<1, 128, 0, stream>>>(bsum, nblk, rowptr + N);
    k_apply<<<nblk, 256, 0, stream>>>(counts, N, bsum, rowptr, cursor);
    k_scatter<<<(E + 255) / 256, 256, 0, stream>>>(src, dst, E, cursor, csr);

    // ---- W split+transpose (cursor is dead now) ----
    k_wconv<<<192, 256, 0, stream>>>(W1, w1h, w1l, NLAYERS * HID * HID);
    k_wconv<<<192, 256, 0, stream>>>(W2, w2h, w2l, NLAYERS * HID * HID);

    for (int l = 0; l < NLAYERS; ++l) {
        const float* hin = (l == 0) ? x : h[l - 1];
        const float* asc = (l == 0) ? idaff : (ss + (l - 1) * 256);

        k_agg_csr<<<(N + 3) / 4, 256, 0, stream>>>(
            rowptr, csr, (const float2*)hin, asc, epsg, l, z0h, z0l, N);

        k_gin_mlp<<<(N + 63) / 64, 256, 0, stream>>>(
            z0h, z0l,
            w1h + (size_t)l * 16384, w1l + (size_t)l * 16384, b1 + l * HID,
            w2h + (size_t)l * 16384, w2l + (size_t)l * 16384, b2 + l * HID,
            h[l], stats + l * 256, stats + l * 256 + 128, N);

        k_bn_fin<<<1, 128, 0, stream>>>(
            stats + l * 256, stats + l * 256 + 128, gamma, beta, l, N,
            ss + l * 256, ss + l * 256 + 128);
    }

    k_pool<<<NGRAPH, 384, 0, stream>>>(batch, N, h[0], h[1], h[2], ss, g_feat);
    k_mlp<<<NGRAPH, 128, 0, stream>>>(g_feat, l1w, l1b, l2w, l2b, (float*)d_out);
}

// Round 6
// 928.101 us; speedup vs baseline: 9.3223x; 1.0269x over previous
//
#include <hip/hip_runtime.h>

#define HID 128
#define NGRAPH 512
#define NLAYERS 3
#define BN_EPS 1e-5f
#define NPB 256          // nodes per bucket (CSR build)
#define EB 4096          // edges per build block

typedef __attribute__((ext_vector_type(8))) short bf16x8;
typedef __attribute__((ext_vector_type(4))) float f32x4;

__device__ inline unsigned short f2bf(float x) {
    union { float f; unsigned u; } v; v.f = x;
    unsigned r = v.u + 0x7FFFu + ((v.u >> 16) & 1u);
    return (unsigned short)(r >> 16);
}
__device__ inline float bf2f(unsigned short b) {
    union { float f; unsigned u; } v; v.u = ((unsigned)b) << 16; return v.f;
}

// ---------------------------------------------------------------------------
// setup: identity affine (for layer 0) + zero BN stats
// ---------------------------------------------------------------------------
__global__ void k_setup(float* __restrict__ id_scale, float* __restrict__ id_shift,
                        float* __restrict__ stats) {
    int t = threadIdx.x;              // 256 threads
    if (t < 128) { id_scale[t] = 1.0f; id_shift[t] = 0.0f; }
    for (int l = 0; l < NLAYERS; ++l) stats[l * 256 + t] = 0.0f;
}

// ---------------------------------------------------------------------------
// W convert+transpose: Wt[l][n][k] = split_bf16(W[l][k][n]); run once per call
// ---------------------------------------------------------------------------
__global__ void k_wconv(const float* __restrict__ W, ushort* __restrict__ Wth,
                        ushort* __restrict__ Wtl, int total) {
    int e = blockIdx.x * 256 + threadIdx.x;
    if (e >= total) return;
    int l = e >> 14, rem = e & 16383, k = rem >> 7, n = rem & 127;
    float v = W[e];
    ushort hi = f2bf(v);
    ushort lo = f2bf(v - bf2f(hi));
    int o = (l << 14) + (n << 7) + k;
    Wth[o] = hi; Wtl[o] = lo;
}

// ---------------------------------------------------------------------------
// CSR build, deterministic two-level (NO global atomics):
// 1) k_ecount:  per-edge-block LDS hist -> blkcnt[blk][b] (512-wide rows)
// 2) k_btotal:  column totals -> exclusive bucket bases bbase[]; rowptr[N]=E
// 3) k_colscan: per-bucket column exclusive scan: blkcnt[blk][b] becomes the
//               absolute slot base for block blk's edges of bucket b
// 4) k_bscatter: place packed (dlocal,src) pairs (LDS cursor only)
// 5) k_bbuild:  per-bucket node count/scan -> rowptr + coalesced csr
// ---------------------------------------------------------------------------
__global__ __launch_bounds__(256) void k_ecount(const int* __restrict__ dst, int E,
                                                int* __restrict__ blkcnt) {
    __shared__ int hist[512];
    int t = threadIdx.x;
    hist[t] = 0; hist[t + 256] = 0;
    __syncthreads();
    int base = blockIdx.x * EB;
    #pragma unroll
    for (int i = 0; i < 16; ++i) {
        int e = base + i * 256 + t;
        if (e < E) atomicAdd(&hist[dst[e] >> 8], 1);
    }
    __syncthreads();
    blkcnt[blockIdx.x * 512 + t]       = hist[t];
    blkcnt[blockIdx.x * 512 + t + 256] = hist[t + 256];
}

__global__ __launch_bounds__(256) void k_btotal(const int* __restrict__ blkcnt, int eblk,
                                                int nb, int E, int* __restrict__ bbase,
                                                int* __restrict__ rowptrN) {
    __shared__ int tot[512];
    int t = threadIdx.x;
    for (int b = t; b < 512; b += 256) {
        int s = 0;
        for (int j = 0; j < eblk; ++j) s += blkcnt[j * 512 + b];
        tot[b] = s;
    }
    __syncthreads();
    if (t == 0) {
        int run = 0;
        for (int b = 0; b < nb; ++b) { int c = tot[b]; tot[b] = run; run += c; }
        *rowptrN = E;
    }
    __syncthreads();
    for (int b = t; b < nb; b += 256) bbase[b] = tot[b];
    if (t == 0) bbase[nb] = E;
}

__global__ __launch_bounds__(256) void k_colscan(int* __restrict__ blkcnt, int eblk,
                                                 const int* __restrict__ bbase) {
    __shared__ int sh[512];
    int t = threadIdx.x;
    int b = blockIdx.x;
    for (int j = t; j < eblk; j += 256) sh[j] = blkcnt[j * 512 + b];
    __syncthreads();
    if (t == 0) {
        int run = bbase[b];
        for (int j = 0; j < eblk; ++j) { int c = sh[j]; sh[j] = run; run += c; }
    }
    __syncthreads();
    for (int j = t; j < eblk; j += 256) blkcnt[j * 512 + b] = sh[j];
}

__global__ __launch_bounds__(256) void k_bscatter(const int* __restrict__ src,
                                                  const int* __restrict__ dst, int E,
                                                  const int* __restrict__ blkcnt,
                                                  unsigned* __restrict__ pairs) {
    __shared__ int hist[512];    // local cursor (starts at 0)
    __shared__ int lbase[512];   // absolute base for this block's chunk per bucket
    int t = threadIdx.x;
    hist[t] = 0; hist[t + 256] = 0;
    lbase[t]       = blkcnt[blockIdx.x * 512 + t];
    lbase[t + 256] = blkcnt[blockIdx.x * 512 + t + 256];
    __syncthreads();
    int base = blockIdx.x * EB;
    #pragma unroll
    for (int i = 0; i < 16; ++i) {
        int e = base + i * 256 + t;
        if (e < E) {
            int d = dst[e];
            int b = d >> 8;
            int pos = lbase[b] + atomicAdd(&hist[b], 1);
            pairs[pos] = ((unsigned)(d & 255) << 24) | (unsigned)src[e];
        }
    }
}

__global__ __launch_bounds__(256) void k_bbuild(const unsigned* __restrict__ pairs,
                                                const int* __restrict__ bbase, int N,
                                                int* __restrict__ rowptr, int* __restrict__ csr) {
    __shared__ int cnt[256];
    __shared__ int off[256];
    int t = threadIdx.x;
    int b = blockIdx.x;
    int base = bbase[b], bcount = bbase[b + 1] - base;
    cnt[t] = 0;
    __syncthreads();
    for (int i = t; i < bcount; i += 256) atomicAdd(&cnt[pairs[base + i] >> 24], 1);
    __syncthreads();
    off[t] = cnt[t];
    __syncthreads();
    for (int s = 1; s < 256; s <<= 1) {
        int v = (t >= s) ? off[t - s] : 0;
        __syncthreads();
        off[t] += v;
        __syncthreads();
    }
    int excl = (t == 0) ? 0 : off[t - 1];
    int node = b * NPB + t;
    if (node < N) rowptr[node] = base + excl;
    cnt[t] = excl;                      // becomes per-node cursor
    __syncthreads();
    for (int i = t; i < bcount; i += 256) {
        unsigned p = pairs[base + i];
        int dl = p >> 24;
        int pos = base + atomicAdd(&cnt[dl], 1);
        csr[pos] = (int)(p & 0xFFFFFFu);
    }
}

// ---------------------------------------------------------------------------
// CSR aggregation + folded input affine; emits z0 as bf16 hi/lo pair.
//   z0[i] = sc * ((1+eps)*h_i + sum_{j->i} h_j) + (1+eps+deg)*sh
// ---------------------------------------------------------------------------
__global__ __launch_bounds__(256) void k_agg_csr(
        const int* __restrict__ rowptr, const int* __restrict__ csr_src,
        const float2* __restrict__ hin, const float* __restrict__ ss,
        const float* __restrict__ eps_gin, int layer,
        ushort* __restrict__ z0h, ushort* __restrict__ z0l, int N) {
    int node = blockIdx.x * 4 + (threadIdx.x >> 6);
    if (node >= N) return;
    int f = threadIdx.x & 63;                      // float2 lane
    float2 sc = ((const float2*)ss)[f];
    float2 sh = ((const float2*)(ss + HID))[f];
    float e1 = 1.0f + eps_gin[layer];
    int beg = rowptr[node], end = rowptr[node + 1];
    float2 hself = hin[(size_t)node * 64 + f];
    float sx = e1 * hself.x, sy = e1 * hself.y;
    int p = beg;
    for (; p + 3 < end; p += 4) {
        int s0 = csr_src[p], s1 = csr_src[p + 1], s2 = csr_src[p + 2], s3 = csr_src[p + 3];
        float2 v0 = hin[(size_t)s0 * 64 + f];
        float2 v1 = hin[(size_t)s1 * 64 + f];
        float2 v2 = hin[(size_t)s2 * 64 + f];
        float2 v3 = hin[(size_t)s3 * 64 + f];
        sx += (v0.x + v1.x) + (v2.x + v3.x);
        sy += (v0.y + v1.y) + (v2.y + v3.y);
    }
    for (; p < end; ++p) {
        int s0 = csr_src[p];
        float2 v0 = hin[(size_t)s0 * 64 + f];
        sx += v0.x; sy += v0.y;
    }
    float c = e1 + (float)(end - beg);
    float rx = sc.x * sx + c * sh.x;
    float ry = sc.y * sy + c * sh.y;
    ushort hx = f2bf(rx); ushort lx = f2bf(rx - bf2f(hx));
    ushort hy = f2bf(ry); ushort ly = f2bf(ry - bf2f(hy));
    ((unsigned*)z0h)[(size_t)node * 64 + f] = ((unsigned)hy << 16) | hx;
    ((unsigned*)z0l)[(size_t)node * 64 + f] = ((unsigned)ly << 16) | lx;
}

// ---------------------------------------------------------------------------
// fused per-layer MLP via MFMA, bf16x3 split (fp32-grade accuracy):
//   h_out = relu(relu(z0@W1+b1)@W2+b2), + BN stats
// Block: 256 thr = 4 waves; tile 64 rows x 128 cols; wave owns 32 cols.
// LDS 64KB: W chunk [128n][32d] hi+lo (32KB) | A/z1 region (32KB).
// XOR swizzle (4-dword granularity, keyed by row&7) -> conflict-free b128.
// ---------------------------------------------------------------------------
__global__ __launch_bounds__(256) void k_gin_mlp(
        const ushort* __restrict__ z0h, const ushort* __restrict__ z0l,
        const ushort* __restrict__ w1h, const ushort* __restrict__ w1l,
        const float* __restrict__ b1,
        const ushort* __restrict__ w2h, const ushort* __restrict__ w2l,
        const float* __restrict__ b2,
        float* __restrict__ Hout, float* __restrict__ stat_sum, float* __restrict__ stat_sq,
        int N) {
    __shared__ __align__(16) ushort smem[32768];   // 64 KB
    uint4* s4 = (uint4*)smem;
    // uint4 regions: Wh 0..1023 | Wl 1024..2047 | Ah 2048..2559 | Al 2560..3071
    // z1 overlay:    Zh 2048..3071 (us 16384)   | Zl 3072..4095 (us 24576)

    const int t = threadIdx.x;
    const int lane = t & 63;
    const int wv = t >> 6;
    const int li = lane & 15;
    const int kq = lane >> 4;
    const int n0 = wv * 32;
    const int row0 = blockIdx.x * 64;
    const int swz = (li & 7) * 4;      // fragment-read xor (row&7 == li&7 for all tiles)

    const int sr = t >> 3;             // staging: row 0..31 per pass
    const int sl = t & 7;              // staging: 4-dword column

    f32x4 acc[4][2];
    #pragma unroll
    for (int i = 0; i < 4; ++i) {
        acc[i][0] = (f32x4){0.f, 0.f, 0.f, 0.f};
        acc[i][1] = (f32x4){0.f, 0.f, 0.f, 0.f};
    }

    // ---------------- GEMM1: z1 = z0 @ W1 ----------------
    for (int ch = 0; ch < 2; ++ch) {
        __syncthreads();
        #pragma unroll
        for (int i = 0; i < 2; ++i) {           // A chunk: 64 rows x 8 uint4
            int r = sr + i * 32;
            int gi = (row0 + r) * 16 + ch * 8 + sl;
            uint4 vh = make_uint4(0, 0, 0, 0), vl = vh;
            if (row0 + r < N) { vh = ((const uint4*)z0h)[gi]; vl = ((const uint4*)z0l)[gi]; }
            int d = r * 8 + (sl ^ (r & 7));
            s4[2048 + d] = vh;
            s4[2560 + d] = vl;
        }
        #pragma unroll
        for (int i = 0; i < 4; ++i) {           // W chunk: 128 rows x 8 uint4
            int n = sr + i * 32;
            int gi = n * 16 + ch * 8 + sl;
            int d = n * 8 + (sl ^ (n & 7));
            s4[d]        = ((const uint4*)w1h)[gi];
            s4[1024 + d] = ((const uint4*)w1l)[gi];
        }
        __syncthreads();
        #pragma unroll
        for (int ks = 0; ks < 2; ++ks) {
            int aoff = (ks * 16 + kq * 4) ^ swz;
            bf16x8 ah[4], al[4], bh[2], bl[2];
            #pragma unroll
            for (int mt = 0; mt < 4; ++mt) {
                int idx = ((mt * 16 + li) * 32 + aoff) * 2;
                ah[mt] = *(const bf16x8*)&smem[16384 + idx];
                al[mt] = *(const bf16x8*)&smem[20480 + idx];
            }
            #pragma unroll
            for (int nt = 0; nt < 2; ++nt) {
                int idx = ((n0 + nt * 16 + li) * 32 + aoff) * 2;
                bh[nt] = *(const bf16x8*)&smem[idx];
                bl[nt] = *(const bf16x8*)&smem[8192 + idx];
            }
            #pragma unroll
            for (int mt = 0; mt < 4; ++mt)
                #pragma unroll
                for (int nt = 0; nt < 2; ++nt) {
                    acc[mt][nt] = __builtin_amdgcn_mfma_f32_16x16x32_bf16(ah[mt], bh[nt], acc[mt][nt], 0, 0, 0);
                    acc[mt][nt] = __builtin_amdgcn_mfma_f32_16x16x32_bf16(ah[mt], bl[nt], acc[mt][nt], 0, 0, 0);
                    acc[mt][nt] = __builtin_amdgcn_mfma_f32_16x16x32_bf16(al[mt], bh[nt], acc[mt][nt], 0, 0, 0);
                }
        }
    }

    // ---- z1 = relu(acc + b1) -> Z region (A-layout, bf16 hi/lo, swizzled) ----
    float bz0 = b1[n0 + li], bz1 = b1[n0 + 16 + li];
    __syncthreads();                    // all GEMM1 LDS reads done before overwrite
    #pragma unroll
    for (int mt = 0; mt < 4; ++mt) {
        #pragma unroll
        for (int nt = 0; nt < 2; ++nt) {
            int c = n0 + nt * 16 + li;
            int dk = c >> 1;
            int halfbase = (dk >> 5) * 32;
            int dlow = dk & 31;
            int codd = c & 1;
            float bias = nt ? bz1 : bz0;
            #pragma unroll
            for (int reg = 0; reg < 4; ++reg) {
                int r = mt * 16 + kq * 4 + reg;
                float v = fmaxf(acc[mt][nt][reg] + bias, 0.f);
                ushort hi = f2bf(v);
                ushort lo = f2bf(v - bf2f(hi));
                int us = (r * 64 + halfbase + (dlow ^ ((r & 7) * 4))) * 2 + codd;
                smem[16384 + us] = hi;
                smem[24576 + us] = lo;
            }
        }
    }
    #pragma unroll
    for (int i = 0; i < 4; ++i) {
        acc[i][0] = (f32x4){0.f, 0.f, 0.f, 0.f};
        acc[i][1] = (f32x4){0.f, 0.f, 0.f, 0.f};
    }

    // ---------------- GEMM2: z2 = z1 @ W2 ----------------
    for (int ch = 0; ch < 2; ++ch) {
        __syncthreads();                // ch0: z1 writes visible; ch1: W2(0) reads done
        #pragma unroll
        for (int i = 0; i < 4; ++i) {
            int n = sr + i * 32;
            int gi = n * 16 + ch * 8 + sl;
            int d = n * 8 + (sl ^ (n & 7));
            s4[d]        = ((const uint4*)w2h)[gi];
            s4[1024 + d] = ((const uint4*)w2l)[gi];
        }
        __syncthreads();
        #pragma unroll
        for (int ks = 0; ks < 2; ++ks) {
            int aoff = (ks * 16 + kq * 4) ^ swz;
            bf16x8 ah[4], al[4], bh[2], bl[2];
            #pragma unroll
            for (int mt = 0; mt < 4; ++mt) {
                int idx = ((mt * 16 + li) * 64 + ch * 32 + aoff) * 2;
                ah[mt] = *(const bf16x8*)&smem[16384 + idx];
                al[mt] = *(const bf16x8*)&smem[24576 + idx];
            }
            #pragma unroll
            for (int nt = 0; nt < 2; ++nt) {
                int idx = ((n0 + nt * 16 + li) * 32 + aoff) * 2;
                bh[nt] = *(const bf16x8*)&smem[idx];
                bl[nt] = *(const bf16x8*)&smem[8192 + idx];
            }
            #pragma unroll
            for (int mt = 0; mt < 4; ++mt)
                #pragma unroll
                for (int nt = 0; nt < 2; ++nt) {
                    acc[mt][nt] = __builtin_amdgcn_mfma_f32_16x16x32_bf16(ah[mt], bh[nt], acc[mt][nt], 0, 0, 0);
                    acc[mt][nt] = __builtin_amdgcn_mfma_f32_16x16x32_bf16(ah[mt], bl[nt], acc[mt][nt], 0, 0, 0);
                    acc[mt][nt] = __builtin_amdgcn_mfma_f32_16x16x32_bf16(al[mt], bh[nt], acc[mt][nt], 0, 0, 0);
                }
        }
    }

    // ---- epilogue: bias+relu, store h, BN stats (shuffle-reduce over quads) ----
    float bb0 = b2[n0 + li], bb1 = b2[n0 + 16 + li];
    float s0 = 0.f, q0 = 0.f, s1 = 0.f, q1 = 0.f;
    #pragma unroll
    for (int mt = 0; mt < 4; ++mt) {
        #pragma unroll
        for (int reg = 0; reg < 4; ++reg) {
            int grow = row0 + mt * 16 + kq * 4 + reg;
            if (grow < N) {
                float v0 = fmaxf(acc[mt][0][reg] + bb0, 0.f);
                float v1 = fmaxf(acc[mt][1][reg] + bb1, 0.f);
                Hout[(size_t)grow * HID + n0 + li]      = v0;
                Hout[(size_t)grow * HID + n0 + 16 + li] = v1;
                s0 += v0; q0 += v0 * v0; s1 += v1; q1 += v1 * v1;
            }
        }
    }
    s0 += __shfl_xor(s0, 16); s0 += __shfl_xor(s0, 32);
    q0 += __shfl_xor(q0, 16); q0 += __shfl_xor(q0, 32);
    s1 += __shfl_xor(s1, 16); s1 += __shfl_xor(s1, 32);
    q1 += __shfl_xor(q1, 16); q1 += __shfl_xor(q1, 32);
    if (kq == 0) {
        unsafeAtomicAdd(&stat_sum[n0 + li], s0);
        unsafeAtomicAdd(&stat_sq[n0 + li], q0);
        unsafeAtomicAdd(&stat_sum[n0 + 16 + li], s1);
        unsafeAtomicAdd(&stat_sq[n0 + 16 + li], q1);
    }
}

// ---------------------------------------------------------------------------
// fold BN into per-feature scale/shift
// ---------------------------------------------------------------------------
__global__ void k_bn_fin(const float* __restrict__ stat_sum, const float* __restrict__ stat_sq,
                         const float* __restrict__ gamma, const float* __restrict__ beta,
                         int layer, int N, float* __restrict__ scale, float* __restrict__ shift) {
    int f = threadIdx.x;   // 128
    float invn = 1.0f / (float)N;
    float mu = stat_sum[f] * invn;
    float var = stat_sq[f] * invn - mu * mu;
    float inv = rsqrtf(var + BN_EPS);
    float sc = gamma[layer * HID + f] * inv;
    scale[f] = sc;
    shift[f] = beta[layer * HID + f] - mu * sc;
}

// ---------------------------------------------------------------------------
// global mean pool over concat(h0,h1,h2) with BN affine folded out of the loop
// ---------------------------------------------------------------------------
__global__ __launch_bounds__(384) void k_pool(const int* __restrict__ batch, int N,
                       const float* __restrict__ h0, const float* __restrict__ h1,
                       const float* __restrict__ h2, const float* __restrict__ ss,
                       float* __restrict__ g_feat) {
    int g = blockIdx.x;
    int f = threadIdx.x;            // 0..383
    int start, end;
    { int lo = 0, hi = N; while (lo < hi) { int m = (lo + hi) >> 1; if (batch[m] < g) lo = m + 1; else hi = m; } start = lo; }
    { int lo = start, hi = N; while (lo < hi) { int m = (lo + hi) >> 1; if (batch[m] < g + 1) lo = m + 1; else hi = m; } end = lo; }
    int l = f >> 7, c = f & 127;
    const float* hb = (l == 0) ? h0 : (l == 1) ? h1 : h2;
    float sc = ss[l * 256 + c];
    float sh = ss[l * 256 + 128 + c];
    float sum = 0.f;
    for (int i = start; i < end; ++i) sum += hb[(size_t)i * HID + c];
    float cnt = (float)(end - start);
    g_feat[g * 384 + f] = (sum * sc + sh * cnt) / fmaxf(cnt, 1.0f);
}

// ---------------------------------------------------------------------------
// final MLP
// ---------------------------------------------------------------------------
__global__ __launch_bounds__(128) void k_mlp(const float* __restrict__ g_feat,
                     const float* __restrict__ w1, const float* __restrict__ b1,
                     const float* __restrict__ w2, const float* __restrict__ b2,
                     float* __restrict__ out) {
    __shared__ float gl[384];
    __shared__ float hh[128];
    int g = blockIdx.x, t = threadIdx.x;   // 128 threads
    for (int i = t; i < 384; i += 128) gl[i] = g_feat[g * 384 + i];
    __syncthreads();
    float acc = b1[t];
    for (int k = 0; k < 384; ++k) acc = fmaf(gl[k], w1[k * HID + t], acc);
    hh[t] = fmaxf(acc, 0.f);
    __syncthreads();
    if (t < 10) {
        float a2 = b2[t];
        for (int k = 0; k < 128; ++k) a2 = fmaf(hh[k], w2[k * 10 + t], a2);
        out[g * 10 + t] = a2;
    }
}

// ---------------------------------------------------------------------------
extern "C" void kernel_launch(void* const* d_in, const int* in_sizes, int n_in,
                              void* d_out, int out_size, void* d_ws, size_t ws_size,
                              hipStream_t stream) {
    const float* x     = (const float*)d_in[0];
    const int*   ei    = (const int*)d_in[1];
    const int*   batch = (const int*)d_in[2];
    const float* W1    = (const float*)d_in[3];
    const float* b1    = (const float*)d_in[4];
    const float* W2    = (const float*)d_in[5];
    const float* b2    = (const float*)d_in[6];
    const float* gamma = (const float*)d_in[7];
    const float* beta  = (const float*)d_in[8];
    const float* epsg  = (const float*)d_in[9];
    const float* l1w   = (const float*)d_in[10];
    const float* l1b   = (const float*)d_in[11];
    const float* l2w   = (const float*)d_in[12];
    const float* l2b   = (const float*)d_in[13];

    const int N = in_sizes[0] / HID;
    const int E = in_sizes[1] / 2;
    const int* src = ei;
    const int* dst = ei + E;
    const int nb = (N + NPB - 1) / NPB;           // <= 512
    const int eblk = (E + EB - 1) / EB;           // <= 512

    float* w = (float*)d_ws;
    const size_t NF = (size_t)N * HID;
    float* zbuf   = w;                                       // z0 hi/lo; pairs+blkcnt overlay pre-agg
    float* h[3]   = { w + NF, w + 2 * NF, w + 3 * NF };
    float* stats  = w + 4 * NF;       // 3 * 256
    float* ss     = stats + 768;      // 3 * 256
    float* idaff  = ss + 768;         // 256
    float* g_feat = idaff + 256;      // 512 * 384
    int*   rowptr = (int*)(g_feat + (size_t)NGRAPH * 384);   // N + 1
    int*   csr    = rowptr + N + 1;                          // E
    int*   bbase  = csr + E;                                 // nb + 1
    ushort* wt  = (ushort*)(((uintptr_t)(bbase + nb + 1) + 15) & ~(uintptr_t)15);
    ushort* w1h = wt;
    ushort* w1l = wt + 49152;
    ushort* w2h = wt + 98304;
    ushort* w2l = wt + 147456;

    unsigned* pairs  = (unsigned*)zbuf;             // E uints   (dead before first k_agg_csr)
    int*      blkcnt = (int*)(w + 2 * 1024 * 1024); // eblk*512  (also inside zbuf region)

    ushort* z0h = (ushort*)zbuf;          // NF ushorts
    ushort* z0l = z0h + NF;               // NF ushorts

    k_setup<<<1, 256, 0, stream>>>(idaff, idaff + 128, stats);

    // ---- build CSR (deterministic, no global atomics) ----
    k_ecount<<<eblk, 256, 0, stream>>>(dst, E, blkcnt);
    k_btotal<<<1, 256, 0, stream>>>(blkcnt, eblk, nb, E, bbase, rowptr + N);
    k_colscan<<<nb, 256, 0, stream>>>(blkcnt, eblk, bbase);
    k_bscatter<<<eblk, 256, 0, stream>>>(src, dst, E, blkcnt, pairs);
    k_bbuild<<<nb, 256, 0, stream>>>(pairs, bbase, N, rowptr, csr);

    // ---- W split+transpose ----
    k_wconv<<<192, 256, 0, stream>>>(W1, w1h, w1l, NLAYERS * HID * HID);
    k_wconv<<<192, 256, 0, stream>>>(W2, w2h, w2l, NLAYERS * HID * HID);

    for (int l = 0; l < NLAYERS; ++l) {
        const float* hin = (l == 0) ? x : h[l - 1];
        const float* asc = (l == 0) ? idaff : (ss + (l - 1) * 256);

        k_agg_csr<<<(N + 3) / 4, 256, 0, stream>>>(
            rowptr, csr, (const float2*)hin, asc, epsg, l, z0h, z0l, N);

        k_gin_mlp<<<(N + 63) / 64, 256, 0, stream>>>(
            z0h, z0l,
            w1h + (size_t)l * 16384, w1l + (size_t)l * 16384, b1 + l * HID,
            w2h + (size_t)l * 16384, w2l + (size_t)l * 16384, b2 + l * HID,
            h[l], stats + l * 256, stats + l * 256 + 128, N);

        k_bn_fin<<<1, 128, 0, stream>>>(
            stats + l * 256, stats + l * 256 + 128, gamma, beta, l, N,
            ss + l * 256, ss + l * 256 + 128);
    }

    k_pool<<<NGRAPH, 384, 0, stream>>>(batch, N, h[0], h[1], h[2], ss, g_feat);
    k_mlp<<<NGRAPH, 128, 0, stream>>>(g_feat, l1w, l1b, l2w, l2b, (float*)d_out);
}

// Round 7
// 920.953 us; speedup vs baseline: 9.3947x; 1.0078x over previous
//
#include <hip/hip_runtime.h>

#define HID 128
#define NGRAPH 512
#define NLAYERS 3
#define BN_EPS 1e-5f
#define NPB 256          // nodes per bucket (CSR build)
#define EB 4096          // edges per build block

typedef __attribute__((ext_vector_type(8))) short bf16x8;
typedef __attribute__((ext_vector_type(4))) float f32x4;

__device__ inline unsigned short f2bf(float x) {
    union { float f; unsigned u; } v; v.f = x;
    unsigned r = v.u + 0x7FFFu + ((v.u >> 16) & 1u);
    return (unsigned short)(r >> 16);
}
__device__ inline float bf2f(unsigned short b) {
    union { float f; unsigned u; } v; v.u = ((unsigned)b) << 16; return v.f;
}

// ---------------------------------------------------------------------------
// setup: identity affine (for layer 0) + zero BN stats
// ---------------------------------------------------------------------------
__global__ void k_setup(float* __restrict__ id_scale, float* __restrict__ id_shift,
                        float* __restrict__ stats) {
    int t = threadIdx.x;              // 256 threads
    if (t < 128) { id_scale[t] = 1.0f; id_shift[t] = 0.0f; }
    for (int l = 0; l < NLAYERS; ++l) stats[l * 256 + t] = 0.0f;
}

// ---------------------------------------------------------------------------
// W convert+transpose: Wt[l][n][k] = split_bf16(W[l][k][n]); run once per call
// ---------------------------------------------------------------------------
__global__ void k_wconv(const float* __restrict__ W, ushort* __restrict__ Wth,
                        ushort* __restrict__ Wtl, int total) {
    int e = blockIdx.x * 256 + threadIdx.x;
    if (e >= total) return;
    int l = e >> 14, rem = e & 16383, k = rem >> 7, n = rem & 127;
    float v = W[e];
    ushort hi = f2bf(v);
    ushort lo = f2bf(v - bf2f(hi));
    int o = (l << 14) + (n << 7) + k;
    Wth[o] = hi; Wtl[o] = lo;
}

// ---------------------------------------------------------------------------
// CSR build, deterministic two-level (NO global atomics)
// ---------------------------------------------------------------------------
__global__ __launch_bounds__(256) void k_ecount(const int* __restrict__ dst, int E,
                                                int* __restrict__ blkcnt) {
    __shared__ int hist[512];
    int t = threadIdx.x;
    hist[t] = 0; hist[t + 256] = 0;
    __syncthreads();
    int base = blockIdx.x * EB;
    #pragma unroll
    for (int i = 0; i < 16; ++i) {
        int e = base + i * 256 + t;
        if (e < E) atomicAdd(&hist[dst[e] >> 8], 1);
    }
    __syncthreads();
    blkcnt[blockIdx.x * 512 + t]       = hist[t];
    blkcnt[blockIdx.x * 512 + t + 256] = hist[t + 256];
}

__global__ __launch_bounds__(256) void k_btotal(const int* __restrict__ blkcnt, int eblk,
                                                int nb, int E, int* __restrict__ bbase,
                                                int* __restrict__ rowptrN) {
    __shared__ int tot[512];
    int t = threadIdx.x;
    for (int b = t; b < 512; b += 256) {
        int s = 0;
        for (int j = 0; j < eblk; ++j) s += blkcnt[j * 512 + b];
        tot[b] = s;
    }
    __syncthreads();
    if (t == 0) {
        int run = 0;
        for (int b = 0; b < nb; ++b) { int c = tot[b]; tot[b] = run; run += c; }
        *rowptrN = E;
    }
    __syncthreads();
    for (int b = t; b < nb; b += 256) bbase[b] = tot[b];
    if (t == 0) bbase[nb] = E;
}

__global__ __launch_bounds__(256) void k_colscan(int* __restrict__ blkcnt, int eblk,
                                                 const int* __restrict__ bbase) {
    __shared__ int sh[512];
    int t = threadIdx.x;
    int b = blockIdx.x;
    for (int j = t; j < eblk; j += 256) sh[j] = blkcnt[j * 512 + b];
    __syncthreads();
    if (t == 0) {
        int run = bbase[b];
        for (int j = 0; j < eblk; ++j) { int c = sh[j]; sh[j] = run; run += c; }
    }
    __syncthreads();
    for (int j = t; j < eblk; j += 256) blkcnt[j * 512 + b] = sh[j];
}

__global__ __launch_bounds__(256) void k_bscatter(const int* __restrict__ src,
                                                  const int* __restrict__ dst, int E,
                                                  const int* __restrict__ blkcnt,
                                                  unsigned* __restrict__ pairs) {
    __shared__ int hist[512];    // local cursor (starts at 0)
    __shared__ int lbase[512];   // absolute base for this block's chunk per bucket
    int t = threadIdx.x;
    hist[t] = 0; hist[t + 256] = 0;
    lbase[t]       = blkcnt[blockIdx.x * 512 + t];
    lbase[t + 256] = blkcnt[blockIdx.x * 512 + t + 256];
    __syncthreads();
    int base = blockIdx.x * EB;
    #pragma unroll
    for (int i = 0; i < 16; ++i) {
        int e = base + i * 256 + t;
        if (e < E) {
            int d = dst[e];
            int b = d >> 8;
            int pos = lbase[b] + atomicAdd(&hist[b], 1);
            pairs[pos] = ((unsigned)(d & 255) << 24) | (unsigned)src[e];
        }
    }
}

__global__ __launch_bounds__(256) void k_bbuild(const unsigned* __restrict__ pairs,
                                                const int* __restrict__ bbase, int N,
                                                int* __restrict__ rowptr, int* __restrict__ csr) {
    __shared__ int cnt[256];
    __shared__ int off[256];
    int t = threadIdx.x;
    int b = blockIdx.x;
    int base = bbase[b], bcount = bbase[b + 1] - base;
    cnt[t] = 0;
    __syncthreads();
    for (int i = t; i < bcount; i += 256) atomicAdd(&cnt[pairs[base + i] >> 24], 1);
    __syncthreads();
    off[t] = cnt[t];
    __syncthreads();
    for (int s = 1; s < 256; s <<= 1) {
        int v = (t >= s) ? off[t - s] : 0;
        __syncthreads();
        off[t] += v;
        __syncthreads();
    }
    int excl = (t == 0) ? 0 : off[t - 1];
    int node = b * NPB + t;
    if (node < N) rowptr[node] = base + excl;
    cnt[t] = excl;                      // becomes per-node cursor
    __syncthreads();
    for (int i = t; i < bcount; i += 256) {
        unsigned p = pairs[base + i];
        int dl = p >> 24;
        int pos = base + atomicAdd(&cnt[dl], 1);
        csr[pos] = (int)(p & 0xFFFFFFu);
    }
}

// ---------------------------------------------------------------------------
// CSR aggregation + folded input affine; emits z0 as bf16 hi/lo pair.
//   z0[i] = sc * ((1+eps)*h_i + sum_{j->i} h_j) + (1+eps+deg)*sh
// 32 lanes x float4 per row (512B), 2 nodes/wave, 8 nodes per 256-block.
// 4-deep neighbor unroll -> 64B/lane outstanding.
// ---------------------------------------------------------------------------
__global__ __launch_bounds__(256) void k_agg_csr(
        const int* __restrict__ rowptr, const int* __restrict__ csr_src,
        const float4* __restrict__ hin4, const float* __restrict__ ss,
        const float* __restrict__ eps_gin, int layer,
        ushort* __restrict__ z0h, ushort* __restrict__ z0l, int N) {
    int node = blockIdx.x * 8 + (threadIdx.x >> 5);
    if (node >= N) return;
    int f = threadIdx.x & 31;                      // float4 lane (32 x 16B = 512B row)
    float4 sc = ((const float4*)ss)[f];
    float4 sh = ((const float4*)(ss + HID))[f];
    float e1 = 1.0f + eps_gin[layer];
    int beg = rowptr[node], end = rowptr[node + 1];
    float4 hv = hin4[(size_t)node * 32 + f];
    float ax = e1 * hv.x, ay = e1 * hv.y, az = e1 * hv.z, aw = e1 * hv.w;
    int p = beg;
    for (; p + 3 < end; p += 4) {
        int s0 = csr_src[p], s1 = csr_src[p + 1], s2 = csr_src[p + 2], s3 = csr_src[p + 3];
        float4 v0 = hin4[(size_t)s0 * 32 + f];
        float4 v1 = hin4[(size_t)s1 * 32 + f];
        float4 v2 = hin4[(size_t)s2 * 32 + f];
        float4 v3 = hin4[(size_t)s3 * 32 + f];
        ax += (v0.x + v1.x) + (v2.x + v3.x);
        ay += (v0.y + v1.y) + (v2.y + v3.y);
        az += (v0.z + v1.z) + (v2.z + v3.z);
        aw += (v0.w + v1.w) + (v2.w + v3.w);
    }
    for (; p < end; ++p) {
        int s0 = csr_src[p];
        float4 v0 = hin4[(size_t)s0 * 32 + f];
        ax += v0.x; ay += v0.y; az += v0.z; aw += v0.w;
    }
    float c = e1 + (float)(end - beg);
    float r0 = sc.x * ax + c * sh.x;
    float r1 = sc.y * ay + c * sh.y;
    float r2 = sc.z * az + c * sh.z;
    float r3 = sc.w * aw + c * sh.w;
    ushort h0 = f2bf(r0), h1 = f2bf(r1), h2 = f2bf(r2), h3 = f2bf(r3);
    ushort l0 = f2bf(r0 - bf2f(h0)), l1 = f2bf(r1 - bf2f(h1));
    ushort l2 = f2bf(r2 - bf2f(h2)), l3 = f2bf(r3 - bf2f(h3));
    uint2 ph, pl;
    ph.x = ((unsigned)h1 << 16) | h0;  ph.y = ((unsigned)h3 << 16) | h2;
    pl.x = ((unsigned)l1 << 16) | l0;  pl.y = ((unsigned)l3 << 16) | l2;
    ((uint2*)z0h)[(size_t)node * 32 + f] = ph;
    ((uint2*)z0l)[(size_t)node * 32 + f] = pl;
}

// ---------------------------------------------------------------------------
// fused per-layer MLP via MFMA, bf16x3 split (fp32-grade accuracy):
//   h_out = relu(relu(z0@W1+b1)@W2+b2), + BN stats
// Block: 256 thr = 4 waves; tile 64 rows x 128 cols; wave owns 32 cols.
// LDS 64KB: W chunk [128n][32d] hi+lo (32KB) | A/z1 region (32KB).
// XOR swizzle (4-dword granularity, keyed by row&7) -> conflict-free b128.
// ---------------------------------------------------------------------------
__global__ __launch_bounds__(256) void k_gin_mlp(
        const ushort* __restrict__ z0h, const ushort* __restrict__ z0l,
        const ushort* __restrict__ w1h, const ushort* __restrict__ w1l,
        const float* __restrict__ b1,
        const ushort* __restrict__ w2h, const ushort* __restrict__ w2l,
        const float* __restrict__ b2,
        float* __restrict__ Hout, float* __restrict__ stat_sum, float* __restrict__ stat_sq,
        int N) {
    __shared__ __align__(16) ushort smem[32768];   // 64 KB
    uint4* s4 = (uint4*)smem;
    // uint4 regions: Wh 0..1023 | Wl 1024..2047 | Ah 2048..2559 | Al 2560..3071
    // z1 overlay:    Zh 2048..3071 (us 16384)   | Zl 3072..4095 (us 24576)

    const int t = threadIdx.x;
    const int lane = t & 63;
    const int wv = t >> 6;
    const int li = lane & 15;
    const int kq = lane >> 4;
    const int n0 = wv * 32;
    const int row0 = blockIdx.x * 64;
    const int swz = (li & 7) * 4;      // fragment-read xor (row&7 == li&7 for all tiles)

    const int sr = t >> 3;             // staging: row 0..31 per pass
    const int sl = t & 7;              // staging: 4-dword column

    f32x4 acc[4][2];
    #pragma unroll
    for (int i = 0; i < 4; ++i) {
        acc[i][0] = (f32x4){0.f, 0.f, 0.f, 0.f};
        acc[i][1] = (f32x4){0.f, 0.f, 0.f, 0.f};
    }

    // ---------------- GEMM1: z1 = z0 @ W1 ----------------
    for (int ch = 0; ch < 2; ++ch) {
        __syncthreads();
        #pragma unroll
        for (int i = 0; i < 2; ++i) {           // A chunk: 64 rows x 8 uint4
            int r = sr + i * 32;
            int gi = (row0 + r) * 16 + ch * 8 + sl;
            uint4 vh = make_uint4(0, 0, 0, 0), vl = vh;
            if (row0 + r < N) { vh = ((const uint4*)z0h)[gi]; vl = ((const uint4*)z0l)[gi]; }
            int d = r * 8 + (sl ^ (r & 7));
            s4[2048 + d] = vh;
            s4[2560 + d] = vl;
        }
        #pragma unroll
        for (int i = 0; i < 4; ++i) {           // W chunk: 128 rows x 8 uint4
            int n = sr + i * 32;
            int gi = n * 16 + ch * 8 + sl;
            int d = n * 8 + (sl ^ (n & 7));
            s4[d]        = ((const uint4*)w1h)[gi];
            s4[1024 + d] = ((const uint4*)w1l)[gi];
        }
        __syncthreads();
        #pragma unroll
        for (int ks = 0; ks < 2; ++ks) {
            int aoff = (ks * 16 + kq * 4) ^ swz;
            bf16x8 ah[4], al[4], bh[2], bl[2];
            #pragma unroll
            for (int mt = 0; mt < 4; ++mt) {
                int idx = ((mt * 16 + li) * 32 + aoff) * 2;
                ah[mt] = *(const bf16x8*)&smem[16384 + idx];
                al[mt] = *(const bf16x8*)&smem[20480 + idx];
            }
            #pragma unroll
            for (int nt = 0; nt < 2; ++nt) {
                int idx = ((n0 + nt * 16 + li) * 32 + aoff) * 2;
                bh[nt] = *(const bf16x8*)&smem[idx];
                bl[nt] = *(const bf16x8*)&smem[8192 + idx];
            }
            #pragma unroll
            for (int mt = 0; mt < 4; ++mt)
                #pragma unroll
                for (int nt = 0; nt < 2; ++nt) {
                    acc[mt][nt] = __builtin_amdgcn_mfma_f32_16x16x32_bf16(ah[mt], bh[nt], acc[mt][nt], 0, 0, 0);
                    acc[mt][nt] = __builtin_amdgcn_mfma_f32_16x16x32_bf16(ah[mt], bl[nt], acc[mt][nt], 0, 0, 0);
                    acc[mt][nt] = __builtin_amdgcn_mfma_f32_16x16x32_bf16(al[mt], bh[nt], acc[mt][nt], 0, 0, 0);
                }
        }
    }

    // ---- z1 = relu(acc + b1) -> Z region (A-layout, bf16 hi/lo, swizzled) ----
    float bz0 = b1[n0 + li], bz1 = b1[n0 + 16 + li];
    __syncthreads();                    // all GEMM1 LDS reads done before overwrite
    #pragma unroll
    for (int mt = 0; mt < 4; ++mt) {
        #pragma unroll
        for (int nt = 0; nt < 2; ++nt) {
            int c = n0 + nt * 16 + li;
            int dk = c >> 1;
            int halfbase = (dk >> 5) * 32;
            int dlow = dk & 31;
            int codd = c & 1;
            float bias = nt ? bz1 : bz0;
            #pragma unroll
            for (int reg = 0; reg < 4; ++reg) {
                int r = mt * 16 + kq * 4 + reg;
                float v = fmaxf(acc[mt][nt][reg] + bias, 0.f);
                ushort hi = f2bf(v);
                ushort lo = f2bf(v - bf2f(hi));
                int us = (r * 64 + halfbase + (dlow ^ ((r & 7) * 4))) * 2 + codd;
                smem[16384 + us] = hi;
                smem[24576 + us] = lo;
            }
        }
    }
    #pragma unroll
    for (int i = 0; i < 4; ++i) {
        acc[i][0] = (f32x4){0.f, 0.f, 0.f, 0.f};
        acc[i][1] = (f32x4){0.f, 0.f, 0.f, 0.f};
    }

    // ---------------- GEMM2: z2 = z1 @ W2 ----------------
    for (int ch = 0; ch < 2; ++ch) {
        __syncthreads();                // ch0: z1 writes visible; ch1: W2(0) reads done
        #pragma unroll
        for (int i = 0; i < 4; ++i) {
            int n = sr + i * 32;
            int gi = n * 16 + ch * 8 + sl;
            int d = n * 8 + (sl ^ (n & 7));
            s4[d]        = ((const uint4*)w2h)[gi];
            s4[1024 + d] = ((const uint4*)w2l)[gi];
        }
        __syncthreads();
        #pragma unroll
        for (int ks = 0; ks < 2; ++ks) {
            int aoff = (ks * 16 + kq * 4) ^ swz;
            bf16x8 ah[4], al[4], bh[2], bl[2];
            #pragma unroll
            for (int mt = 0; mt < 4; ++mt) {
                int idx = ((mt * 16 + li) * 64 + ch * 32 + aoff) * 2;
                ah[mt] = *(const bf16x8*)&smem[16384 + idx];
                al[mt] = *(const bf16x8*)&smem[24576 + idx];
            }
            #pragma unroll
            for (int nt = 0; nt < 2; ++nt) {
                int idx = ((n0 + nt * 16 + li) * 32 + aoff) * 2;
                bh[nt] = *(const bf16x8*)&smem[idx];
                bl[nt] = *(const bf16x8*)&smem[8192 + idx];
            }
            #pragma unroll
            for (int mt = 0; mt < 4; ++mt)
                #pragma unroll
                for (int nt = 0; nt < 2; ++nt) {
                    acc[mt][nt] = __builtin_amdgcn_mfma_f32_16x16x32_bf16(ah[mt], bh[nt], acc[mt][nt], 0, 0, 0);
                    acc[mt][nt] = __builtin_amdgcn_mfma_f32_16x16x32_bf16(ah[mt], bl[nt], acc[mt][nt], 0, 0, 0);
                    acc[mt][nt] = __builtin_amdgcn_mfma_f32_16x16x32_bf16(al[mt], bh[nt], acc[mt][nt], 0, 0, 0);
                }
        }
    }

    // ---- epilogue: bias+relu, store h, BN stats (shuffle-reduce over quads) ----
    float bb0 = b2[n0 + li], bb1 = b2[n0 + 16 + li];
    float s0 = 0.f, q0 = 0.f, s1 = 0.f, q1 = 0.f;
    #pragma unroll
    for (int mt = 0; mt < 4; ++mt) {
        #pragma unroll
        for (int reg = 0; reg < 4; ++reg) {
            int grow = row0 + mt * 16 + kq * 4 + reg;
            if (grow < N) {
                float v0 = fmaxf(acc[mt][0][reg] + bb0, 0.f);
                float v1 = fmaxf(acc[mt][1][reg] + bb1, 0.f);
                Hout[(size_t)grow * HID + n0 + li]      = v0;
                Hout[(size_t)grow * HID + n0 + 16 + li] = v1;
                s0 += v0; q0 += v0 * v0; s1 += v1; q1 += v1 * v1;
            }
        }
    }
    s0 += __shfl_xor(s0, 16); s0 += __shfl_xor(s0, 32);
    q0 += __shfl_xor(q0, 16); q0 += __shfl_xor(q0, 32);
    s1 += __shfl_xor(s1, 16); s1 += __shfl_xor(s1, 32);
    q1 += __shfl_xor(q1, 16); q1 += __shfl_xor(q1, 32);
    if (kq == 0) {
        unsafeAtomicAdd(&stat_sum[n0 + li], s0);
        unsafeAtomicAdd(&stat_sq[n0 + li], q0);
        unsafeAtomicAdd(&stat_sum[n0 + 16 + li], s1);
        unsafeAtomicAdd(&stat_sq[n0 + 16 + li], q1);
    }
}

// ---------------------------------------------------------------------------
// fold BN into per-feature scale/shift
// ---------------------------------------------------------------------------
__global__ void k_bn_fin(const float* __restrict__ stat_sum, const float* __restrict__ stat_sq,
                         const float* __restrict__ gamma, const float* __restrict__ beta,
                         int layer, int N, float* __restrict__ scale, float* __restrict__ shift) {
    int f = threadIdx.x;   // 128
    float invn = 1.0f / (float)N;
    float mu = stat_sum[f] * invn;
    float var = stat_sq[f] * invn - mu * mu;
    float inv = rsqrtf(var + BN_EPS);
    float sc = gamma[layer * HID + f] * inv;
    scale[f] = sc;
    shift[f] = beta[layer * HID + f] - mu * sc;
}

// ---------------------------------------------------------------------------
// global mean pool over concat(h0,h1,h2) with BN affine folded out of the loop
// ---------------------------------------------------------------------------
__global__ __launch_bounds__(384) void k_pool(const int* __restrict__ batch, int N,
                       const float* __restrict__ h0, const float* __restrict__ h1,
                       const float* __restrict__ h2, const float* __restrict__ ss,
                       float* __restrict__ g_feat) {
    int g = blockIdx.x;
    int f = threadIdx.x;            // 0..383
    int start, end;
    { int lo = 0, hi = N; while (lo < hi) { int m = (lo + hi) >> 1; if (batch[m] < g) lo = m + 1; else hi = m; } start = lo; }
    { int lo = start, hi = N; while (lo < hi) { int m = (lo + hi) >> 1; if (batch[m] < g + 1) lo = m + 1; else hi = m; } end = lo; }
    int l = f >> 7, c = f & 127;
    const float* hb = (l == 0) ? h0 : (l == 1) ? h1 : h2;
    float sc = ss[l * 256 + c];
    float sh = ss[l * 256 + 128 + c];
    float sum = 0.f;
    for (int i = start; i < end; ++i) sum += hb[(size_t)i * HID + c];
    float cnt = (float)(end - start);
    g_feat[g * 384 + f] = (sum * sc + sh * cnt) / fmaxf(cnt, 1.0f);
}

// ---------------------------------------------------------------------------
// final MLP
// ---------------------------------------------------------------------------
__global__ __launch_bounds__(128) void k_mlp(const float* __restrict__ g_feat,
                     const float* __restrict__ w1, const float* __restrict__ b1,
                     const float* __restrict__ w2, const float* __restrict__ b2,
                     float* __restrict__ out) {
    __shared__ float gl[384];
    __shared__ float hh[128];
    int g = blockIdx.x, t = threadIdx.x;   // 128 threads
    for (int i = t; i < 384; i += 128) gl[i] = g_feat[g * 384 + i];
    __syncthreads();
    float acc = b1[t];
    for (int k = 0; k < 384; ++k) acc = fmaf(gl[k], w1[k * HID + t], acc);
    hh[t] = fmaxf(acc, 0.f);
    __syncthreads();
    if (t < 10) {
        float a2 = b2[t];
        for (int k = 0; k < 128; ++k) a2 = fmaf(hh[k], w2[k * 10 + t], a2);
        out[g * 10 + t] = a2;
    }
}

// ---------------------------------------------------------------------------
extern "C" void kernel_launch(void* const* d_in, const int* in_sizes, int n_in,
                              void* d_out, int out_size, void* d_ws, size_t ws_size,
                              hipStream_t stream) {
    const float* x     = (const float*)d_in[0];
    const int*   ei    = (const int*)d_in[1];
    const int*   batch = (const int*)d_in[2];
    const float* W1    = (const float*)d_in[3];
    const float* b1    = (const float*)d_in[4];
    const float* W2    = (const float*)d_in[5];
    const float* b2    = (const float*)d_in[6];
    const float* gamma = (const float*)d_in[7];
    const float* beta  = (const float*)d_in[8];
    const float* epsg  = (const float*)d_in[9];
    const float* l1w   = (const float*)d_in[10];
    const float* l1b   = (const float*)d_in[11];
    const float* l2w   = (const float*)d_in[12];
    const float* l2b   = (const float*)d_in[13];

    const int N = in_sizes[0] / HID;
    const int E = in_sizes[1] / 2;
    const int* src = ei;
    const int* dst = ei + E;
    const int nb = (N + NPB - 1) / NPB;           // <= 512
    const int eblk = (E + EB - 1) / EB;           // <= 512

    float* w = (float*)d_ws;
    const size_t NF = (size_t)N * HID;
    float* zbuf   = w;                                       // z0 hi/lo; pairs+blkcnt overlay pre-agg
    float* h[3]   = { w + NF, w + 2 * NF, w + 3 * NF };
    float* stats  = w + 4 * NF;       // 3 * 256
    float* ss     = stats + 768;      // 3 * 256
    float* idaff  = ss + 768;         // 256
    float* g_feat = idaff + 256;      // 512 * 384
    int*   rowptr = (int*)(g_feat + (size_t)NGRAPH * 384);   // N + 1
    int*   csr    = rowptr + N + 1;                          // E
    int*   bbase  = csr + E;                                 // nb + 1
    ushort* wt  = (ushort*)(((uintptr_t)(bbase + nb + 1) + 15) & ~(uintptr_t)15);
    ushort* w1h = wt;
    ushort* w1l = wt + 49152;
    ushort* w2h = wt + 98304;
    ushort* w2l = wt + 147456;

    unsigned* pairs  = (unsigned*)zbuf;             // E uints   (dead before first k_agg_csr)
    int*      blkcnt = (int*)(w + 2 * 1024 * 1024); // eblk*512  (also inside zbuf region)

    ushort* z0h = (ushort*)zbuf;          // NF ushorts
    ushort* z0l = z0h + NF;               // NF ushorts

    k_setup<<<1, 256, 0, stream>>>(idaff, idaff + 128, stats);

    // ---- build CSR (deterministic, no global atomics) ----
    k_ecount<<<eblk, 256, 0, stream>>>(dst, E, blkcnt);
    k_btotal<<<1, 256, 0, stream>>>(blkcnt, eblk, nb, E, bbase, rowptr + N);
    k_colscan<<<nb, 256, 0, stream>>>(blkcnt, eblk, bbase);
    k_bscatter<<<eblk, 256, 0, stream>>>(src, dst, E, blkcnt, pairs);
    k_bbuild<<<nb, 256, 0, stream>>>(pairs, bbase, N, rowptr, csr);

    // ---- W split+transpose ----
    k_wconv<<<192, 256, 0, stream>>>(W1, w1h, w1l, NLAYERS * HID * HID);
    k_wconv<<<192, 256, 0, stream>>>(W2, w2h, w2l, NLAYERS * HID * HID);

    for (int l = 0; l < NLAYERS; ++l) {
        const float* hin = (l == 0) ? x : h[l - 1];
        const float* asc = (l == 0) ? idaff : (ss + (l - 1) * 256);

        k_agg_csr<<<(N + 7) / 8, 256, 0, stream>>>(
            rowptr, csr, (const float4*)hin, asc, epsg, l, z0h, z0l, N);

        k_gin_mlp<<<(N + 63) / 64, 256, 0, stream>>>(
            z0h, z0l,
            w1h + (size_t)l * 16384, w1l + (size_t)l * 16384, b1 + l * HID,
            w2h + (size_t)l * 16384, w2l + (size_t)l * 16384, b2 + l * HID,
            h[l], stats + l * 256, stats + l * 256 + 128, N);

        k_bn_fin<<<1, 128, 0, stream>>>(
            stats + l * 256, stats + l * 256 + 128, gamma, beta, l, N,
            ss + l * 256, ss + l * 256 + 128);
    }

    k_pool<<<NGRAPH, 384, 0, stream>>>(batch, N, h[0], h[1], h[2], ss, g_feat);
    k_mlp<<<NGRAPH, 128, 0, stream>>>(g_feat, l1w, l1b, l2w, l2b, (float*)d_out);
}